// Round 1
// baseline (2235.100 us; speedup 1.0000x reference)
//
#include <hip/hip_runtime.h>
#include <math.h>

namespace {

constexpr int B = 8, D = 49, C = 512, N = 12, H = 256, E = 144;
constexpr int M_BD  = B * D;        // 392
constexpr int M_BND = B * N * D;    // 4704
constexpr float BN_EPS = 1e-5f;
constexpr float ATT_SCALE = 0.0625f; // (C/2)^-0.5 = 256^-0.5

// ---------------- generic tiled SGEMM (64x64 tile, K-panel 16) ----------------
__global__ __launch_bounds__(256)
void sgemm_bias(const float* __restrict__ A, const float* __restrict__ Bm,
                const float* __restrict__ bias, float* __restrict__ Cm,
                int M, int Nn, int K,
                long long sA, long long sB, long long sBias, long long sC)
{
  const int z = blockIdx.z;
  A += z * sA; Bm += z * sB; Cm += z * sC;
  const float* bp = bias ? bias + z * sBias : nullptr;

  __shared__ float As[16][65];
  __shared__ float Bs[16][65];
  const int tid = threadIdx.x;
  const int tm = tid >> 4, tn = tid & 15;
  const int row0 = blockIdx.x * 64, col0 = blockIdx.y * 64;

  float acc[4][4] = {};
  for (int k0 = 0; k0 < K; k0 += 16) {
    for (int i = tid; i < 64 * 16; i += 256) {
      int r = i >> 4, kk = i & 15;
      int gr = row0 + r;
      float v = 0.f;
      if (gr < M) v = A[(long long)gr * K + k0 + kk];
      As[kk][r] = v;
    }
    for (int i = tid; i < 64 * 16; i += 256) {
      int kk = i >> 6, c = i & 63;
      int gc = col0 + c;
      float v = 0.f;
      if (gc < Nn) v = Bm[(long long)(k0 + kk) * Nn + gc];
      Bs[kk][c] = v;
    }
    __syncthreads();
#pragma unroll
    for (int kk = 0; kk < 16; ++kk) {
      float a[4], bb[4];
#pragma unroll
      for (int i = 0; i < 4; ++i) a[i] = As[kk][tm * 4 + i];
#pragma unroll
      for (int jj = 0; jj < 4; ++jj) bb[jj] = Bs[kk][tn * 4 + jj];
#pragma unroll
      for (int i = 0; i < 4; ++i)
#pragma unroll
        for (int jj = 0; jj < 4; ++jj)
          acc[i][jj] = fmaf(a[i], bb[jj], acc[i][jj]);
    }
    __syncthreads();
  }
#pragma unroll
  for (int i = 0; i < 4; ++i) {
    int r = row0 + tm * 4 + i;
    if (r >= M) continue;
#pragma unroll
    for (int jj = 0; jj < 4; ++jj) {
      int c = col0 + tn * 4 + jj;
      if (c >= Nn) continue;
      float v = acc[i][jj];
      if (bp) v += bp[c];
      Cm[(long long)r * Nn + c] = v;
    }
  }
}

// ---------------- BN stats per (n,c) over the 392 (b,d) rows ----------------
__global__ void bn_stats_nc(const float* __restrict__ h, float* __restrict__ mu,
                            float* __restrict__ rs)
{
  int idx = blockIdx.x * blockDim.x + threadIdx.x;
  if (idx >= N * C) return;
  int n = idx / C, c = idx % C;
  const float* p = h + (long long)n * M_BD * C + c;
  float s = 0.f, q = 0.f;
  for (int r = 0; r < M_BD; ++r) { float v = p[(long long)r * C]; s += v; q += v * v; }
  float m = s / (float)M_BD;
  mu[idx] = m;
  rs[idx] = rsqrtf(q / (float)M_BD - m * m + BN_EPS);
}

// ---------------- f_u = relu(norm(h)), f_v = mean_d f_u ----------------
__global__ __launch_bounds__(256)
void fu_fv(const float* __restrict__ h, const float* __restrict__ mu,
           const float* __restrict__ rs, float* __restrict__ fu,
           float* __restrict__ fv)
{
  const int bid = blockIdx.x;           // b*N+n
  const int b = bid / N, n = bid % N;
  const int tid = threadIdx.x;
  for (int c = tid; c < C; c += 256) {
    float m = mu[n * C + c], r = rs[n * C + c];
    float acc = 0.f;
    for (int d = 0; d < D; ++d) {
      float v = h[((long long)n * M_BD + b * D + d) * C + c];
      v = fmaxf((v - m) * r, 0.f);
      fu[((long long)(b * N + n) * D + d) * C + c] = v;
      acc += v;
    }
    fv[(long long)(b * N + n) * C + c] = acc * (1.0f / (float)D);
  }
}

// ---------------- fam cross-attention: one block per (b,n) ----------------
__global__ __launch_bounds__(256)
void attn_fam(const float* __restrict__ Qg, const float* __restrict__ Kg,
              const float* __restrict__ Vg, float* __restrict__ Og)
{
  const int bid = blockIdx.x;
  const int b = bid / N, n = bid % N;
  const float* Q  = Qg + (long long)(b * N + n) * D * H;
  const float* Kp = Kg + (long long)b * D * H;
  const float* Vp = Vg + (long long)b * D * C;
  float* O = Og + (long long)(b * N + n) * D * C;

  __shared__ float smem[D * 256];       // v tile; q/k tiles fit too (2*49*65=6370)
  __shared__ float s_lds[D][D + 1];
  const int tid = threadIdx.x;

  float sacc[10];
#pragma unroll
  for (int p = 0; p < 10; ++p) sacc[p] = 0.f;

  for (int kc = 0; kc < H; kc += 64) {
    for (int idx = tid; idx < D * 64; idx += 256) {
      int r = idx >> 6, k = idx & 63;
      smem[r * 65 + k]          = Q[r * H + kc + k];
      smem[D * 65 + r * 65 + k] = Kp[r * H + kc + k];
    }
    __syncthreads();
#pragma unroll
    for (int p = 0; p < 10; ++p) {
      int idx = tid + p * 256;
      if (idx < D * D) {
        int di = idx / D, dj = idx - di * D;
        const float* qr = &smem[di * 65];
        const float* kr = &smem[D * 65 + dj * 65];
        float a = 0.f;
#pragma unroll
        for (int k = 0; k < 64; ++k) a = fmaf(qr[k], kr[k], a);
        sacc[p] += a;
      }
    }
    __syncthreads();
  }
#pragma unroll
  for (int p = 0; p < 10; ++p) {
    int idx = tid + p * 256;
    if (idx < D * D) s_lds[idx / D][idx % D] = sacc[p] * ATT_SCALE;
  }
  __syncthreads();
  if (tid < D) {
    float m = -1e30f;
    for (int jj = 0; jj < D; ++jj) m = fmaxf(m, s_lds[tid][jj]);
    float sum = 0.f;
    for (int jj = 0; jj < D; ++jj) { float ev = __expf(s_lds[tid][jj] - m); s_lds[tid][jj] = ev; sum += ev; }
    float inv = 1.f / sum;
    for (int jj = 0; jj < D; ++jj) s_lds[tid][jj] *= inv;
  }
  __syncthreads();

  for (int cc = 0; cc < C; cc += 256) {
    for (int r = 0; r < D; ++r) smem[r * 256 + tid] = Vp[r * C + cc + tid];
    __syncthreads();
    const int cg = cc + tid;
    for (int di0 = 0; di0 < 48; di0 += 4) {
      float t0 = 0, t1 = 0, t2 = 0, t3 = 0;
      for (int dj = 0; dj < D; ++dj) {
        float v = smem[dj * 256 + tid];
        t0 = fmaf(s_lds[di0    ][dj], v, t0);
        t1 = fmaf(s_lds[di0 + 1][dj], v, t1);
        t2 = fmaf(s_lds[di0 + 2][dj], v, t2);
        t3 = fmaf(s_lds[di0 + 3][dj], v, t3);
      }
      O[(di0    ) * C + cg] = t0;
      O[(di0 + 1) * C + cg] = t1;
      O[(di0 + 2) * C + cg] = t2;
      O[(di0 + 3) * C + cg] = t3;
    }
    {
      float t = 0.f;
      for (int dj = 0; dj < D; ++dj) t = fmaf(s_lds[48][dj], smem[dj * 256 + tid], t);
      O[48 * C + cg] = t;
    }
    __syncthreads();
  }
}

// ---------------- b2full = arm_bv @ ep_w + ep_b ----------------
__global__ void b2full_k(const float* __restrict__ bv, const float* __restrict__ epw,
                         const float* __restrict__ epb, float* __restrict__ b2)
{
  int c = blockIdx.x * blockDim.x + threadIdx.x;
  if (c >= C) return;
  float s = epb[c];
  for (int k = 0; k < C; ++k) s = fmaf(bv[k], epw[k * C + c], s);
  b2[c] = s;
}

// ------- edge attention: block per (b,i,j); t = a@vfe never hits global -------
__global__ __launch_bounds__(256)
void attn_edge(const float* __restrict__ Qg, const float* __restrict__ Kg,
               const float* __restrict__ Vg, float* __restrict__ S1,
               float* __restrict__ eS)
{
  const int bid = blockIdx.x;           // b*E + e
  const int b = bid / E, e = bid % E;
  const int i = e / N, j = e % N;
  const float* Q  = Qg + (long long)(b * N + j) * D * H;  // start-gather -> node j
  const float* Kp = Kg + (long long)(b * N + i) * D * H;  // end-gather -> node i
  const float* Vp = Vg + (long long)(b * N + i) * D * C;

  __shared__ float smem[D * 256];
  __shared__ float s_lds[D][D + 1];
  const int tid = threadIdx.x;

  float sacc[10];
#pragma unroll
  for (int p = 0; p < 10; ++p) sacc[p] = 0.f;

  for (int kc = 0; kc < H; kc += 64) {
    for (int idx = tid; idx < D * 64; idx += 256) {
      int r = idx >> 6, k = idx & 63;
      smem[r * 65 + k]          = Q[r * H + kc + k];
      smem[D * 65 + r * 65 + k] = Kp[r * H + kc + k];
    }
    __syncthreads();
#pragma unroll
    for (int p = 0; p < 10; ++p) {
      int idx = tid + p * 256;
      if (idx < D * D) {
        int di = idx / D, dj = idx - di * D;
        const float* qr = &smem[di * 65];
        const float* kr = &smem[D * 65 + dj * 65];
        float a = 0.f;
#pragma unroll
        for (int k = 0; k < 64; ++k) a = fmaf(qr[k], kr[k], a);
        sacc[p] += a;
      }
    }
    __syncthreads();
  }
#pragma unroll
  for (int p = 0; p < 10; ++p) {
    int idx = tid + p * 256;
    if (idx < D * D) s_lds[idx / D][idx % D] = sacc[p] * ATT_SCALE;
  }
  __syncthreads();
  if (tid < D) {
    float m = -1e30f;
    for (int jj = 0; jj < D; ++jj) m = fmaxf(m, s_lds[tid][jj]);
    float sum = 0.f;
    for (int jj = 0; jj < D; ++jj) { float ev = __expf(s_lds[tid][jj] - m); s_lds[tid][jj] = ev; sum += ev; }
    float inv = 1.f / sum;
    for (int jj = 0; jj < D; ++jj) s_lds[tid][jj] *= inv;
  }
  __syncthreads();

  float st = 0.f, st2 = 0.f;
  for (int cc = 0; cc < C; cc += 256) {
    for (int r = 0; r < D; ++r) smem[r * 256 + tid] = Vp[r * C + cc + tid];
    __syncthreads();
    const int cg = cc + tid;
    float s1 = 0.f;
    for (int di0 = 0; di0 < 48; di0 += 4) {
      float t0 = 0, t1 = 0, t2 = 0, t3 = 0;
      for (int dj = 0; dj < D; ++dj) {
        float v = smem[dj * 256 + tid];
        t0 = fmaf(s_lds[di0    ][dj], v, t0);
        t1 = fmaf(s_lds[di0 + 1][dj], v, t1);
        t2 = fmaf(s_lds[di0 + 2][dj], v, t2);
        t3 = fmaf(s_lds[di0 + 3][dj], v, t3);
      }
      s1  += t0 + t1 + t2 + t3;
      st2 += t0 * t0 + t1 * t1 + t2 * t2 + t3 * t3;
    }
    {
      float t = 0.f;
      for (int dj = 0; dj < D; ++dj) t = fmaf(s_lds[48][dj], smem[dj * 256 + tid], t);
      s1 += t; st2 += t * t;
    }
    st += s1;
    S1[(long long)bid * C + cg] = s1;
    __syncthreads();
  }
  for (int off = 32; off; off >>= 1) { st += __shfl_down(st, off); st2 += __shfl_down(st2, off); }
  __shared__ float r0[4], r1[4];
  int wid = tid >> 6, lane = tid & 63;
  if (lane == 0) { r0[wid] = st; r1[wid] = st2; }
  __syncthreads();
  if (tid == 0) {
    eS[bid * 2 + 0] = r0[0] + r0[1] + r0[2] + r0[3];
    eS[bid * 2 + 1] = r1[0] + r1[1] + r1[2] + r1[3];
  }
}

// ---------------- per-e BN constants for f_e ----------------
__global__ void edge_me(const float* __restrict__ eS, float* __restrict__ me,
                        float* __restrict__ rve)
{
  int e = blockIdx.x * blockDim.x + threadIdx.x;
  if (e >= E) return;
  float s = 0.f, q = 0.f;
  for (int b = 0; b < B; ++b) { s += eS[(b * E + e) * 2]; q += eS[(b * E + e) * 2 + 1]; }
  const float inv = 1.f / (float)(B * D * C);
  float m = s * inv;
  me[e] = m;
  rve[e] = rsqrtf(q * inv - m * m + BN_EPS);
}

// ---------------- cosine-similarity mask, one block per b ----------------
__global__ __launch_bounds__(256)
void mask_k(const float* __restrict__ fv, float* __restrict__ mask)
{
  const int b = blockIdx.x;
  __shared__ float fl[N][C];
  __shared__ float adj[N][N];
  __shared__ float nrm[N];
  __shared__ float dis[N];
  const int tid = threadIdx.x;
  for (int idx = tid; idx < N * C; idx += 256)
    fl[idx / C][idx % C] = fv[(long long)b * N * C + idx];
  __syncthreads();
  if (tid < N * N) {
    int i = tid / N, j = tid % N;
    float s = 0.f;
    for (int k = 0; k < C; ++k) s += fl[i][k] * fl[j][k];
    adj[i][j] = s;
  }
  __syncthreads();
  if (tid < N) nrm[tid] = fmaxf(sqrtf(adj[tid][tid]), 1e-12f);
  __syncthreads();
  if (tid < N * N) {
    int i = tid / N, j = tid % N;
    adj[i][j] = adj[i][j] / (nrm[i] * nrm[j]);
  }
  __syncthreads();
  if (tid < N) {
    float s = 0.f;
    for (int j = 0; j < N; ++j) s += adj[tid][j];
    dis[tid] = rsqrtf(s);
  }
  __syncthreads();
  if (tid < N * N) {
    int i = tid / N, j = tid % N;
    mask[b * E + tid] = adj[i][j] * dis[i] * dis[j];
  }
}

// ---------------- f_e = (S1/D - me)*rve * mask ----------------
__global__ void fe_k(const float* __restrict__ S1, const float* __restrict__ me,
                     const float* __restrict__ rve, const float* __restrict__ mask,
                     float* __restrict__ fe)
{
  long long idx = (long long)blockIdx.x * 256 + threadIdx.x;
  if (idx >= (long long)B * E * C) return;
  long long be = idx / C;
  int e = (int)(be % E);
  fe[idx] = (S1[idx] * (1.0f / (float)D) - me[e]) * rve[e] * mask[be];
}

// ---------------- GNN: agg = A[i] + B[j] + EW[e], BN stats per e ----------------
__global__ __launch_bounds__(256)
void agg_stats(const float* __restrict__ Aw, const float* __restrict__ Bw,
               const float* __restrict__ EW, float* __restrict__ agg,
               float* __restrict__ mu_e, float* __restrict__ rs_e)
{
  const int e = blockIdx.x;
  const int i = e / N, j = e % N;
  const int tid = threadIdx.x;
  float s = 0.f, q = 0.f;
  for (int idx = tid; idx < B * C; idx += 256) {
    int b = idx >> 9, c = idx & 511;
    float v = Aw[(b * N + i) * C + c] + Bw[(b * N + j) * C + c]
            + EW[((long long)b * E + e) * C + c];
    agg[((long long)b * E + e) * C + c] = v;
    s += v; q += v * v;
  }
  for (int off = 32; off; off >>= 1) { s += __shfl_down(s, off); q += __shfl_down(q, off); }
  __shared__ float r0[4], r1[4];
  int wid = tid >> 6, lane = tid & 63;
  if (lane == 0) { r0[wid] = s; r1[wid] = q; }
  __syncthreads();
  if (tid == 0) {
    float ss = r0[0] + r0[1] + r0[2] + r0[3];
    float qq = r1[0] + r1[1] + r1[2] + r1[3];
    float m = ss / (float)(B * C);
    mu_e[e] = m;
    rs_e[e] = rsqrtf(qq / (float)(B * C) - m * m + BN_EPS);
  }
}

__global__ void ed_update(float* __restrict__ ed, const float* __restrict__ agg,
                          const float* __restrict__ mu_e, const float* __restrict__ rs_e)
{
  long long idx = (long long)blockIdx.x * 256 + threadIdx.x;
  if (idx >= (long long)B * E * C) return;
  int e = (int)((idx / C) % E);
  float v = (agg[idx] - mu_e[e]) * rs_e[e];
  ed[idx] += fmaxf(v, 0.f);
}

// ------- sigmoid -> softmax over j -> msg, pre = U + msg; block per (b,i) -------
__global__ __launch_bounds__(256)
void msg_k(const float* __restrict__ ed, const float* __restrict__ Vw,
           const float* __restrict__ Uw, float* __restrict__ pre)
{
  const int bid = blockIdx.x;
  const int b = bid / N, i = bid % N;
  const int tid = threadIdx.x;
  for (int c = tid; c < C; c += 256) {
    float sv[N];
    float m = -1e30f;
    for (int jn = 0; jn < N; ++jn) {
      float xx = ed[((long long)b * E + i * N + jn) * C + c];
      float sg = 1.f / (1.f + __expf(-xx));
      sv[jn] = sg;
      m = fmaxf(m, sg);
    }
    float sum = 0.f;
    for (int jn = 0; jn < N; ++jn) { float ev = __expf(sv[jn] - m); sv[jn] = ev; sum += ev; }
    float acc = 0.f;
    for (int jn = 0; jn < N; ++jn) acc = fmaf(sv[jn], Vw[(b * N + jn) * C + c], acc);
    acc /= (sum * (float)N);
    pre[(b * N + i) * C + c] = Uw[(b * N + i) * C + c] + acc;
  }
}

__global__ __launch_bounds__(256)
void node_stats(const float* __restrict__ pre, float* __restrict__ mu_i,
                float* __restrict__ rs_i)
{
  const int i = blockIdx.x;
  const int tid = threadIdx.x;
  float s = 0.f, q = 0.f;
  for (int idx = tid; idx < B * C; idx += 256) {
    int b = idx >> 9, c = idx & 511;
    float v = pre[(b * N + i) * C + c];
    s += v; q += v * v;
  }
  for (int off = 32; off; off >>= 1) { s += __shfl_down(s, off); q += __shfl_down(q, off); }
  __shared__ float r0[4], r1[4];
  int wid = tid >> 6, lane = tid & 63;
  if (lane == 0) { r0[wid] = s; r1[wid] = q; }
  __syncthreads();
  if (tid == 0) {
    float ss = r0[0] + r0[1] + r0[2] + r0[3];
    float qq = r1[0] + r1[1] + r1[2] + r1[3];
    float m = ss / (float)(B * C);
    mu_i[i] = m;
    rs_i[i] = rsqrtf(qq / (float)(B * C) - m * m + BN_EPS);
  }
}

__global__ void xv_update(float* __restrict__ xv, const float* __restrict__ pre,
                          const float* __restrict__ mu_i, const float* __restrict__ rs_i)
{
  long long idx = (long long)blockIdx.x * 256 + threadIdx.x;
  if (idx >= (long long)B * N * C) return;
  int i = (int)((idx / C) % N);
  float v = xv[idx] + (pre[idx] - mu_i[i]) * rs_i[i];
  xv[idx] = fmaxf(v, 0.f);
}

// ---------------- cosine classifier ----------------
__global__ __launch_bounds__(256)
void cl_k(const float* __restrict__ xv, const float* __restrict__ sc,
          float* __restrict__ out)
{
  const int bid = blockIdx.x;
  const int b = bid / N, i = bid % N;
  const int tid = threadIdx.x;
  float sxx = 0.f, sss = 0.f, sxs = 0.f;
  for (int c = tid; c < C; c += 256) {
    float xvv = xv[(long long)(b * N + i) * C + c];
    float scv = fmaxf(sc[i * C + c], 0.f);
    sxx += xvv * xvv; sss += scv * scv; sxs += xvv * scv;
  }
  for (int off = 32; off; off >>= 1) {
    sxx += __shfl_down(sxx, off);
    sss += __shfl_down(sss, off);
    sxs += __shfl_down(sxs, off);
  }
  __shared__ float r0[4], r1[4], r2[4];
  int wid = tid >> 6, lane = tid & 63;
  if (lane == 0) { r0[wid] = sxx; r1[wid] = sss; r2[wid] = sxs; }
  __syncthreads();
  if (tid == 0) {
    float a = r0[0] + r0[1] + r0[2] + r0[3];
    float s = r1[0] + r1[1] + r1[2] + r1[3];
    float p = r2[0] + r2[1] + r2[2] + r2[3];
    float nx = fmaxf(sqrtf(a), 1e-12f);
    float ns = fmaxf(sqrtf(s), 1e-12f);
    out[b * N + i] = p / (nx * ns);
  }
}

// ---------------- cl_edge = ed @ efc_w + efc_b ----------------
__global__ __launch_bounds__(64)
void cledge_k(const float* __restrict__ ed, const float* __restrict__ w,
              const float* __restrict__ bias, float* __restrict__ out)
{
  const int bid = blockIdx.x;  // b*E + e
  const int lane = threadIdx.x;
  float a0 = 0, a1 = 0, a2 = 0, a3 = 0;
  for (int c = lane; c < C; c += 64) {
    float v = ed[(long long)bid * C + c];
    a0 = fmaf(v, w[c * 4 + 0], a0);
    a1 = fmaf(v, w[c * 4 + 1], a1);
    a2 = fmaf(v, w[c * 4 + 2], a2);
    a3 = fmaf(v, w[c * 4 + 3], a3);
  }
  for (int off = 32; off; off >>= 1) {
    a0 += __shfl_down(a0, off);
    a1 += __shfl_down(a1, off);
    a2 += __shfl_down(a2, off);
    a3 += __shfl_down(a3, off);
  }
  if (lane == 0) {
    out[B * N + bid * 4 + 0] = a0 + bias[0];
    out[B * N + bid * 4 + 1] = a1 + bias[1];
    out[B * N + bid * 4 + 2] = a2 + bias[2];
    out[B * N + bid * 4 + 3] = a3 + bias[3];
  }
}

} // namespace

extern "C" void kernel_launch(void* const* d_in, const int* in_sizes, int n_in,
                              void* d_out, int out_size, void* d_ws, size_t ws_size,
                              hipStream_t stream)
{
  (void)in_sizes; (void)n_in; (void)out_size; (void)ws_size;
  const float* x      = (const float*)d_in[0];
  const float* Wc     = (const float*)d_in[1];
  const float* bc     = (const float*)d_in[2];
  const float* fam_wq = (const float*)d_in[3];
  const float* fam_bq = (const float*)d_in[4];
  const float* fam_wk = (const float*)d_in[5];
  const float* fam_bk = (const float*)d_in[6];
  const float* fam_wv = (const float*)d_in[7];
  const float* fam_bv = (const float*)d_in[8];
  const float* arm_wq = (const float*)d_in[9];
  const float* arm_bq = (const float*)d_in[10];
  const float* arm_wk = (const float*)d_in[11];
  const float* arm_bk = (const float*)d_in[12];
  const float* arm_wv = (const float*)d_in[13];
  const float* arm_bv = (const float*)d_in[14];
  const float* ep_w   = (const float*)d_in[15];
  const float* ep_b   = (const float*)d_in[16];
  const float* g_w[2][5] = {
    {(const float*)d_in[17], (const float*)d_in[18], (const float*)d_in[19],
     (const float*)d_in[20], (const float*)d_in[21]},
    {(const float*)d_in[22], (const float*)d_in[23], (const float*)d_in[24],
     (const float*)d_in[25], (const float*)d_in[26]}};
  const float* sc     = (const float*)d_in[27];
  const float* efc_w  = (const float*)d_in[28];
  const float* efc_b  = (const float*)d_in[29];
  float* out = (float*)d_out;

  float* w = (float*)d_ws;
  size_t off = 0;
  auto alloc = [&](size_t nel) { float* p = w + off; off += nel; return p; };
  float* h_t  = alloc((size_t)N * M_BD * C);
  float* mu_h = alloc((size_t)N * C);
  float* rs_h = alloc((size_t)N * C);
  float* f_u  = alloc((size_t)M_BND * C);
  float* f_v  = alloc((size_t)B * N * C);
  float* q1   = alloc((size_t)M_BND * H);
  float* kx   = alloc((size_t)M_BD * H);
  float* vx   = alloc((size_t)M_BD * C);
  float* feat = alloc((size_t)M_BND * C);
  float* qf   = alloc((size_t)M_BND * H);
  float* kf   = alloc((size_t)M_BND * H);
  float* W2   = alloc((size_t)C * C);
  float* b2   = alloc((size_t)C);
  float* vfe  = alloc((size_t)M_BND * C);
  float* S1   = alloc((size_t)B * E * C);
  float* eS   = alloc((size_t)B * E * 2);
  float* me   = alloc((size_t)E);
  float* rve  = alloc((size_t)E);
  float* mask = alloc((size_t)B * E);
  float* fe   = alloc((size_t)B * E * C);
  float* Aw   = alloc((size_t)B * N * C);
  float* Bw   = alloc((size_t)B * N * C);
  float* Uw   = alloc((size_t)B * N * C);
  float* Vw   = alloc((size_t)B * N * C);
  float* EW   = alloc((size_t)B * E * C);
  float* agg  = alloc((size_t)B * E * C);
  float* mu_e = alloc((size_t)E);
  float* rs_e = alloc((size_t)E);
  float* pre  = alloc((size_t)B * N * C);
  float* mu_i = alloc((size_t)N);
  float* rs_i = alloc((size_t)N);

  dim3 blk(256);

  // per-class linear: h[n] = x @ Wc[n] + bc[n]  (batched over n)
  sgemm_bias<<<dim3(7, 8, 12), blk, 0, stream>>>(x, Wc, bc, h_t, M_BD, C, C,
      0LL, (long long)C * C, (long long)C, (long long)M_BD * C);
  bn_stats_nc<<<dim3((N * C + 255) / 256), blk, 0, stream>>>(h_t, mu_h, rs_h);
  fu_fv<<<dim3(B * N), blk, 0, stream>>>(h_t, mu_h, rs_h, f_u, f_v);

  // fam cross-attn (k,v depend only on x: compute once per b)
  sgemm_bias<<<dim3(74, 4, 1), blk, 0, stream>>>(f_u, fam_wq, fam_bq, q1, M_BND, H, C, 0, 0, 0, 0);
  sgemm_bias<<<dim3(7, 4, 1),  blk, 0, stream>>>(x, fam_wk, fam_bk, kx, M_BD, H, C, 0, 0, 0, 0);
  sgemm_bias<<<dim3(7, 8, 1),  blk, 0, stream>>>(x, fam_wv, fam_bv, vx, M_BD, C, C, 0, 0, 0, 0);
  attn_fam<<<dim3(B * N), blk, 0, stream>>>(q1, kx, vx, feat);

  // arm projections; fold ep_w through v by associativity: vfe = feat@(wv@ep_w) + (bv@ep_w + ep_b)
  sgemm_bias<<<dim3(74, 4, 1), blk, 0, stream>>>(feat, arm_wq, arm_bq, qf, M_BND, H, C, 0, 0, 0, 0);
  sgemm_bias<<<dim3(74, 4, 1), blk, 0, stream>>>(feat, arm_wk, arm_bk, kf, M_BND, H, C, 0, 0, 0, 0);
  sgemm_bias<<<dim3(8, 8, 1),  blk, 0, stream>>>(arm_wv, ep_w, nullptr, W2, C, C, C, 0, 0, 0, 0);
  b2full_k<<<dim3(2), blk, 0, stream>>>(arm_bv, ep_w, ep_b, b2);
  sgemm_bias<<<dim3(74, 8, 1), blk, 0, stream>>>(feat, W2, b2, vfe, M_BND, C, C, 0, 0, 0, 0);

  // per-edge attention + fused BN-stat accumulation (t never materialized)
  attn_edge<<<dim3(B * E), blk, 0, stream>>>(qf, kf, vfe, S1, eS);
  edge_me<<<dim3(1), blk, 0, stream>>>(eS, me, rve);
  mask_k<<<dim3(B), blk, 0, stream>>>(f_v, mask);
  fe_k<<<dim3((B * E * C + 255) / 256), blk, 0, stream>>>(S1, me, rve, mask, fe);

  // two GNN layers (xv lives in f_v; ed lives in fe; both updated in place)
  for (int L = 0; L < 2; ++L) {
    const float* wa = g_w[L][0];
    const float* wb = g_w[L][1];
    const float* we = g_w[L][2];
    const float* wu = g_w[L][3];
    const float* wv = g_w[L][4];
    sgemm_bias<<<dim3(2, 8, 1),  blk, 0, stream>>>(f_v, wa, nullptr, Aw, B * N, C, C, 0, 0, 0, 0);
    sgemm_bias<<<dim3(2, 8, 1),  blk, 0, stream>>>(f_v, wb, nullptr, Bw, B * N, C, C, 0, 0, 0, 0);
    sgemm_bias<<<dim3(2, 8, 1),  blk, 0, stream>>>(f_v, wu, nullptr, Uw, B * N, C, C, 0, 0, 0, 0);
    sgemm_bias<<<dim3(2, 8, 1),  blk, 0, stream>>>(f_v, wv, nullptr, Vw, B * N, C, C, 0, 0, 0, 0);
    sgemm_bias<<<dim3(18, 8, 1), blk, 0, stream>>>(fe, we, nullptr, EW, B * E, C, C, 0, 0, 0, 0);
    agg_stats<<<dim3(E), blk, 0, stream>>>(Aw, Bw, EW, agg, mu_e, rs_e);
    ed_update<<<dim3((B * E * C + 255) / 256), blk, 0, stream>>>(fe, agg, mu_e, rs_e);
    msg_k<<<dim3(B * N), blk, 0, stream>>>(fe, Vw, Uw, pre);
    node_stats<<<dim3(N), blk, 0, stream>>>(pre, mu_i, rs_i);
    xv_update<<<dim3((B * N * C + 255) / 256), blk, 0, stream>>>(f_v, pre, mu_i, rs_i);
  }

  cl_k<<<dim3(B * N), blk, 0, stream>>>(f_v, sc, out);
  cledge_k<<<dim3(B * E), dim3(64), 0, stream>>>(fe, efc_w, efc_b, out);
}

// Round 2
// 440.103 us; speedup vs baseline: 5.0786x; 5.0786x over previous
//
#include <hip/hip_runtime.h>
#include <math.h>

namespace {

constexpr int B = 8, D = 49, C = 512, N = 12, H = 256, E = 144;
constexpr int M_BD  = B * D;        // 392
constexpr int M_BND = B * N * D;    // 4704
constexpr float BN_EPS = 1e-5f;
constexpr float ATT_SCALE = 0.0625f; // (C/2)^-0.5

typedef __attribute__((ext_vector_type(4))) float  floatx4;
typedef __attribute__((ext_vector_type(8))) short  shortx8;

__device__ inline unsigned short f2bf(float f) {
  unsigned u = __float_as_uint(f);
  return (unsigned short)((u + 0x7fffu + ((u >> 16) & 1u)) >> 16);
}

// ---------------- transpose+cast fp32 [K=512][Nn] -> bf16 [Nn][512] ----------------
struct TCJobs {
  const float* src[28];
  unsigned short* dst[28];
  int nn[28];
};

__global__ __launch_bounds__(256)
void tcast_k(TCJobs jobs)
{
  const int z = blockIdx.z;
  const float* src = jobs.src[z];
  unsigned short* dst = jobs.dst[z];
  const int Nn = jobs.nn[z];
  const int tx = blockIdx.x, ty = blockIdx.y;
  if (tx * 32 >= Nn) return;            // K is always 512 -> ty always valid
  __shared__ float t[32][33];
  const int tid = threadIdx.x;
  const int lr = tid >> 5, lc = tid & 31;
#pragma unroll
  for (int p = 0; p < 4; ++p) {
    int k = ty * 32 + p * 8 + lr;
    t[p * 8 + lr][lc] = src[(long long)k * Nn + tx * 32 + lc];
  }
  __syncthreads();
#pragma unroll
  for (int p = 0; p < 4; ++p) {
    int n = tx * 32 + p * 8 + lr;
    dst[(long long)n * 512 + ty * 32 + lc] = f2bf(t[lc][p * 8 + lr]);
  }
}

// ---------------- bf16 MFMA GEMM: A fp32 [M][K], Bt bf16 [Nn][K], C fp32 [M][Nn] ----
// 64x64 tile, BK=64, 4 waves each computing a 32x32 quadrant via 2x2 16x16x32 MFMA.
__global__ __launch_bounds__(256)
void gemm_mfma(const float* __restrict__ A, const unsigned short* __restrict__ Bt,
               const float* __restrict__ bias, float* __restrict__ Co,
               int M, int Nn, int K,
               long long sA, long long sB, long long sBias, long long sC)
{
  const int z = blockIdx.z;
  A  += z * sA; Bt += z * sB; Co += z * sC;
  const float* bp = bias ? bias + z * sBias : nullptr;

  __shared__ short As[64 * 72];   // [row][72] shorts, 144B pitch
  __shared__ short Bs[64 * 72];

  const int tid = threadIdx.x;
  const int row0 = blockIdx.x * 64, col0 = blockIdx.y * 64;
  const int wid = tid >> 6, lane = tid & 63;
  const int wr = wid >> 1, wc = wid & 1;
  const int lr = lane & 15, lg = lane >> 4;

  floatx4 acc00 = {0.f,0.f,0.f,0.f}, acc01 = {0.f,0.f,0.f,0.f};
  floatx4 acc10 = {0.f,0.f,0.f,0.f}, acc11 = {0.f,0.f,0.f,0.f};

  const int r = tid >> 2, seg = tid & 3;
  const int gr = row0 + r, gn = col0 + r;
  const float* apB = A + (long long)gr * K + seg * 16;
  const unsigned short* bpB = Bt + (long long)gn * K + seg * 16;
  short* aw = &As[r * 72 + seg * 16];
  short* bw = &Bs[r * 72 + seg * 16];

  for (int k0 = 0; k0 < K; k0 += 64) {
    float4 fa0, fa1, fa2, fa3;
    if (gr < M) {
      const float4* ap = reinterpret_cast<const float4*>(apB + k0);
      fa0 = ap[0]; fa1 = ap[1]; fa2 = ap[2]; fa3 = ap[3];
    } else {
      fa0 = make_float4(0.f,0.f,0.f,0.f); fa1 = fa0; fa2 = fa0; fa3 = fa0;
    }
    shortx8 w0, w1;
    w0[0]=(short)f2bf(fa0.x); w0[1]=(short)f2bf(fa0.y); w0[2]=(short)f2bf(fa0.z); w0[3]=(short)f2bf(fa0.w);
    w0[4]=(short)f2bf(fa1.x); w0[5]=(short)f2bf(fa1.y); w0[6]=(short)f2bf(fa1.z); w0[7]=(short)f2bf(fa1.w);
    w1[0]=(short)f2bf(fa2.x); w1[1]=(short)f2bf(fa2.y); w1[2]=(short)f2bf(fa2.z); w1[3]=(short)f2bf(fa2.w);
    w1[4]=(short)f2bf(fa3.x); w1[5]=(short)f2bf(fa3.y); w1[6]=(short)f2bf(fa3.z); w1[7]=(short)f2bf(fa3.w);
    shortx8 b0v = *reinterpret_cast<const shortx8*>(bpB + k0);
    shortx8 b1v = *reinterpret_cast<const shortx8*>(bpB + k0 + 8);

    __syncthreads();
    *reinterpret_cast<shortx8*>(aw)     = w0;
    *reinterpret_cast<shortx8*>(aw + 8) = w1;
    *reinterpret_cast<shortx8*>(bw)     = b0v;
    *reinterpret_cast<shortx8*>(bw + 8) = b1v;
    __syncthreads();

#pragma unroll
    for (int kt = 0; kt < 2; ++kt) {
      shortx8 a0 = *reinterpret_cast<const shortx8*>(&As[(wr*32      + lr) * 72 + kt*32 + lg*8]);
      shortx8 a1 = *reinterpret_cast<const shortx8*>(&As[(wr*32 + 16 + lr) * 72 + kt*32 + lg*8]);
      shortx8 bb0 = *reinterpret_cast<const shortx8*>(&Bs[(wc*32      + lr) * 72 + kt*32 + lg*8]);
      shortx8 bb1 = *reinterpret_cast<const shortx8*>(&Bs[(wc*32 + 16 + lr) * 72 + kt*32 + lg*8]);
      acc00 = __builtin_amdgcn_mfma_f32_16x16x32_bf16(a0, bb0, acc00, 0, 0, 0);
      acc01 = __builtin_amdgcn_mfma_f32_16x16x32_bf16(a0, bb1, acc01, 0, 0, 0);
      acc10 = __builtin_amdgcn_mfma_f32_16x16x32_bf16(a1, bb0, acc10, 0, 0, 0);
      acc11 = __builtin_amdgcn_mfma_f32_16x16x32_bf16(a1, bb1, acc11, 0, 0, 0);
    }
  }

  const int colA = col0 + wc * 32 + lr;
  const int colB = colA + 16;
  const float biasA = bp ? bp[colA] : 0.f;
  const float biasB = bp ? bp[colB] : 0.f;
  const int rb0 = row0 + wr * 32 + lg * 4;
  const int rb1 = rb0 + 16;
#pragma unroll
  for (int jj = 0; jj < 4; ++jj) {
    int ra = rb0 + jj, rb = rb1 + jj;
    if (ra < M) {
      Co[(long long)ra * Nn + colA] = acc00[jj] + biasA;
      Co[(long long)ra * Nn + colB] = acc01[jj] + biasB;
    }
    if (rb < M) {
      Co[(long long)rb * Nn + colA] = acc10[jj] + biasA;
      Co[(long long)rb * Nn + colB] = acc11[jj] + biasB;
    }
  }
}

// ---------------- BN stats per (n,c) over the 392 (b,d) rows ----------------
__global__ void bn_stats_nc(const float* __restrict__ h, float* __restrict__ mu,
                            float* __restrict__ rs)
{
  int idx = blockIdx.x * blockDim.x + threadIdx.x;
  if (idx >= N * C) return;
  int n = idx / C, c = idx % C;
  const float* p = h + (long long)n * M_BD * C + c;
  float s = 0.f, q = 0.f;
  for (int rr = 0; rr < M_BD; ++rr) { float v = p[(long long)rr * C]; s += v; q += v * v; }
  float m = s / (float)M_BD;
  mu[idx] = m;
  rs[idx] = rsqrtf(q / (float)M_BD - m * m + BN_EPS);
}

// ---------------- f_u = relu(norm(h)), f_v = mean_d f_u ; grid (B*N, 2) ----------------
__global__ __launch_bounds__(256)
void fu_fv(const float* __restrict__ h, const float* __restrict__ mu,
           const float* __restrict__ rs, float* __restrict__ fu,
           float* __restrict__ fv)
{
  const int bid = blockIdx.x;           // b*N+n
  const int b = bid / N, n = bid % N;
  const int c = blockIdx.y * 256 + threadIdx.x;
  float m = mu[n * C + c], rv = rs[n * C + c];
  float acc = 0.f;
  for (int d = 0; d < D; ++d) {
    float v = h[((long long)n * M_BD + b * D + d) * C + c];
    v = fmaxf((v - m) * rv, 0.f);
    fu[((long long)bid * D + d) * C + c] = v;
    acc += v;
  }
  fv[(long long)bid * C + c] = acc * (1.0f / (float)D);
}

// ---------------- shared QK + softmax for 49x49 attention blocks ----------------
// smem must hold 2*64*60 floats; on exit smem[0..] is probs as [49][52].
__device__ inline void qk_softmax_49(const float* __restrict__ Q,
                                     const float* __restrict__ Kp,
                                     float* __restrict__ smem)
{
  const int tid = threadIdx.x;
  float* sQ = smem;
  float* sK = smem + 64 * 60;
  float a[4][4];
#pragma unroll
  for (int ii = 0; ii < 4; ++ii)
#pragma unroll
    for (int jj = 0; jj < 4; ++jj) a[ii][jj] = 0.f;
  const int di0 = (tid % 13) * 4, dj0 = (tid / 13) * 4;

  for (int kc = 0; kc < H; kc += 64) {
    __syncthreads();
    for (int idx = tid; idx < D * 64; idx += 256) {
      int rr = idx >> 6, k = idx & 63;
      sQ[k * 60 + rr] = Q[rr * H + kc + k];
      sK[k * 60 + rr] = Kp[rr * H + kc + k];
    }
    __syncthreads();
    if (tid < 169) {
#pragma unroll 8
      for (int k = 0; k < 64; ++k) {
        const float4 q4 = *reinterpret_cast<const float4*>(sQ + k * 60 + di0);
        const float4 k4 = *reinterpret_cast<const float4*>(sK + k * 60 + dj0);
        a[0][0]=fmaf(q4.x,k4.x,a[0][0]); a[0][1]=fmaf(q4.x,k4.y,a[0][1]);
        a[0][2]=fmaf(q4.x,k4.z,a[0][2]); a[0][3]=fmaf(q4.x,k4.w,a[0][3]);
        a[1][0]=fmaf(q4.y,k4.x,a[1][0]); a[1][1]=fmaf(q4.y,k4.y,a[1][1]);
        a[1][2]=fmaf(q4.y,k4.z,a[1][2]); a[1][3]=fmaf(q4.y,k4.w,a[1][3]);
        a[2][0]=fmaf(q4.z,k4.x,a[2][0]); a[2][1]=fmaf(q4.z,k4.y,a[2][1]);
        a[2][2]=fmaf(q4.z,k4.z,a[2][2]); a[2][3]=fmaf(q4.z,k4.w,a[2][3]);
        a[3][0]=fmaf(q4.w,k4.x,a[3][0]); a[3][1]=fmaf(q4.w,k4.y,a[3][1]);
        a[3][2]=fmaf(q4.w,k4.z,a[3][2]); a[3][3]=fmaf(q4.w,k4.w,a[3][3]);
      }
    }
  }
  __syncthreads();
  float (*s_lds)[52] = (float (*)[52])smem;
  if (tid < 169) {
#pragma unroll
    for (int ii = 0; ii < 4; ++ii)
#pragma unroll
      for (int jj = 0; jj < 4; ++jj) {
        int di = di0 + ii, dj = dj0 + jj;
        if (di < D && dj < D) s_lds[di][dj] = a[ii][jj] * ATT_SCALE;
      }
  }
  __syncthreads();
  if (tid < D) {
    float m = -1e30f;
    for (int jj = 0; jj < D; ++jj) m = fmaxf(m, s_lds[tid][jj]);
    float s = 0.f;
    for (int jj = 0; jj < D; ++jj) { float ev = __expf(s_lds[tid][jj] - m); s_lds[tid][jj] = ev; s += ev; }
    float inv = 1.f / s;
    for (int jj = 0; jj < D; ++jj) s_lds[tid][jj] *= inv;
  }
  __syncthreads();
}

// PV over a contiguous block of CNT rows starting at `off`; one c-column per thread.
template<int CNT, bool WRITE_O>
__device__ inline void pv_half(const float (*__restrict__ s_lds)[52],
                               const float* __restrict__ Vp, int off, int cg,
                               float* __restrict__ O, float& s1, float& st2)
{
  float t[CNT];
#pragma unroll
  for (int ii = 0; ii < CNT; ++ii) t[ii] = 0.f;
  for (int djc = 0; djc < 48; djc += 4) {
    float v0 = Vp[(djc + 0) * C + cg];
    float v1 = Vp[(djc + 1) * C + cg];
    float v2 = Vp[(djc + 2) * C + cg];
    float v3 = Vp[(djc + 3) * C + cg];
#pragma unroll
    for (int ii = 0; ii < CNT; ++ii) {
      const float4 s4 = *reinterpret_cast<const float4*>(&s_lds[off + ii][djc]);
      t[ii] = fmaf(s4.x, v0, t[ii]); t[ii] = fmaf(s4.y, v1, t[ii]);
      t[ii] = fmaf(s4.z, v2, t[ii]); t[ii] = fmaf(s4.w, v3, t[ii]);
    }
  }
  {
    float v = Vp[48 * C + cg];
#pragma unroll
    for (int ii = 0; ii < CNT; ++ii) t[ii] = fmaf(s_lds[off + ii][48], v, t[ii]);
  }
#pragma unroll
  for (int ii = 0; ii < CNT; ++ii) {
    if (WRITE_O) O[(long long)(off + ii) * C + cg] = t[ii];
    else { s1 += t[ii]; st2 = fmaf(t[ii], t[ii], st2); }
  }
}

// ---------------- fam cross-attention: grid (B*N, 2) ----------------
__global__ __launch_bounds__(256)
void attn_fam(const float* __restrict__ Qg, const float* __restrict__ Kg,
              const float* __restrict__ Vg, float* __restrict__ Og)
{
  __shared__ float smem[64 * 60 * 2];
  const int bid = blockIdx.x;
  const int b = bid / N;
  const float* Q  = Qg + (long long)bid * D * H;
  const float* Kp = Kg + (long long)b * D * H;
  const float* Vp = Vg + (long long)b * D * C;
  float* O = Og + (long long)bid * D * C;

  qk_softmax_49(Q, Kp, smem);
  const float (*s_lds)[52] = (const float (*)[52])smem;
  const int cg = blockIdx.y * 256 + threadIdx.x;
  float d0 = 0.f, d1 = 0.f;
  pv_half<25, true>(s_lds, Vp, 0,  cg, O, d0, d1);
  pv_half<24, true>(s_lds, Vp, 25, cg, O, d0, d1);
}

// ---------------- edge attention: block per (b,i,j); t never hits global ----------------
__global__ __launch_bounds__(256)
void attn_edge(const float* __restrict__ Qg, const float* __restrict__ Kg,
               const float* __restrict__ Vg, float* __restrict__ S1,
               float* __restrict__ eS)
{
  __shared__ float smem[64 * 60 * 2];
  const int bid = blockIdx.x;           // b*E + e
  const int b = bid / E, e = bid % E;
  const int i = e / N, j = e % N;
  const float* Q  = Qg + (long long)(b * N + j) * D * H;  // start-gather -> node j
  const float* Kp = Kg + (long long)(b * N + i) * D * H;  // end-gather -> node i
  const float* Vp = Vg + (long long)(b * N + i) * D * C;

  qk_softmax_49(Q, Kp, smem);
  const float (*s_lds)[52] = (const float (*)[52])smem;
  const int tid = threadIdx.x;

  float st = 0.f, st2 = 0.f;
  for (int cc = 0; cc < C; cc += 256) {
    int cg = cc + tid;
    float s1 = 0.f;
    pv_half<25, false>(s_lds, Vp, 0,  cg, nullptr, s1, st2);
    pv_half<24, false>(s_lds, Vp, 25, cg, nullptr, s1, st2);
    S1[(long long)bid * C + cg] = s1;
    st += s1;
  }
  for (int off = 32; off; off >>= 1) { st += __shfl_down(st, off); st2 += __shfl_down(st2, off); }
  __shared__ float r0[4], r1[4];
  int wid = tid >> 6, lane = tid & 63;
  if (lane == 0) { r0[wid] = st; r1[wid] = st2; }
  __syncthreads();
  if (tid == 0) {
    eS[bid * 2 + 0] = r0[0] + r0[1] + r0[2] + r0[3];
    eS[bid * 2 + 1] = r1[0] + r1[1] + r1[2] + r1[3];
  }
}

// ---------------- b2 = arm_bv @ ep_w + ep_b ----------------
__global__ void b2full_k(const float* __restrict__ bv, const float* __restrict__ epw,
                         const float* __restrict__ epb, float* __restrict__ b2)
{
  int c = blockIdx.x * blockDim.x + threadIdx.x;
  if (c >= C) return;
  float s = epb[c];
  for (int k = 0; k < C; ++k) s = fmaf(bv[k], epw[k * C + c], s);
  b2[c] = s;
}

// ---------------- per-e BN constants for f_e ----------------
__global__ void edge_me(const float* __restrict__ eS, float* __restrict__ me,
                        float* __restrict__ rve)
{
  int e = blockIdx.x * blockDim.x + threadIdx.x;
  if (e >= E) return;
  float s = 0.f, q = 0.f;
  for (int b = 0; b < B; ++b) { s += eS[(b * E + e) * 2]; q += eS[(b * E + e) * 2 + 1]; }
  const float inv = 1.f / (float)(B * D * C);
  float m = s * inv;
  me[e] = m;
  rve[e] = rsqrtf(q * inv - m * m + BN_EPS);
}

// ---------------- cosine-similarity mask, one block per b ----------------
__global__ __launch_bounds__(256)
void mask_k(const float* __restrict__ fv, float* __restrict__ mask)
{
  const int b = blockIdx.x;
  __shared__ float fl[N][C];
  __shared__ float adj[N][N];
  __shared__ float nrm[N];
  __shared__ float dis[N];
  const int tid = threadIdx.x;
  for (int idx = tid; idx < N * C; idx += 256)
    fl[idx / C][idx % C] = fv[(long long)b * N * C + idx];
  __syncthreads();
  if (tid < N * N) {
    int i = tid / N, j = tid % N;
    float s = 0.f;
    for (int k = 0; k < C; ++k) s += fl[i][k] * fl[j][k];
    adj[i][j] = s;
  }
  __syncthreads();
  if (tid < N) nrm[tid] = fmaxf(sqrtf(adj[tid][tid]), 1e-12f);
  __syncthreads();
  if (tid < N * N) {
    int i = tid / N, j = tid % N;
    adj[i][j] = adj[i][j] / (nrm[i] * nrm[j]);
  }
  __syncthreads();
  if (tid < N) {
    float s = 0.f;
    for (int j = 0; j < N; ++j) s += adj[tid][j];
    dis[tid] = rsqrtf(s);
  }
  __syncthreads();
  if (tid < N * N) {
    int i = tid / N, j = tid % N;
    mask[b * E + tid] = adj[i][j] * dis[i] * dis[j];
  }
}

// ---------------- f_e = (S1/D - me)*rve * mask ----------------
__global__ void fe_k(const float* __restrict__ S1, const float* __restrict__ me,
                     const float* __restrict__ rve, const float* __restrict__ mask,
                     float* __restrict__ fe)
{
  long long idx = (long long)blockIdx.x * 256 + threadIdx.x;
  if (idx >= (long long)B * E * C) return;
  long long be = idx / C;
  int e = (int)(be % E);
  fe[idx] = (S1[idx] * (1.0f / (float)D) - me[e]) * rve[e] * mask[be];
}

// ---------------- GNN: agg = A[i] + B[j] + EW[e], BN stats per e ----------------
__global__ __launch_bounds__(256)
void agg_stats(const float* __restrict__ ABUV, const float* __restrict__ EW,
               float* __restrict__ agg, float* __restrict__ mu_e, float* __restrict__ rs_e)
{
  const int e = blockIdx.x;
  const int i = e / N, j = e % N;
  const int tid = threadIdx.x;
  float s = 0.f, q = 0.f;
  for (int idx = tid; idx < B * C; idx += 256) {
    int b = idx >> 9, c = idx & 511;
    float v = ABUV[(long long)(b * N + i) * 2048 + c]
            + ABUV[(long long)(b * N + j) * 2048 + 512 + c]
            + EW[((long long)b * E + e) * C + c];
    agg[((long long)b * E + e) * C + c] = v;
    s += v; q += v * v;
  }
  for (int off = 32; off; off >>= 1) { s += __shfl_down(s, off); q += __shfl_down(q, off); }
  __shared__ float r0[4], r1[4];
  int wid = tid >> 6, lane = tid & 63;
  if (lane == 0) { r0[wid] = s; r1[wid] = q; }
  __syncthreads();
  if (tid == 0) {
    float ss = r0[0] + r0[1] + r0[2] + r0[3];
    float qq = r1[0] + r1[1] + r1[2] + r1[3];
    float m = ss / (float)(B * C);
    mu_e[e] = m;
    rs_e[e] = rsqrtf(qq / (float)(B * C) - m * m + BN_EPS);
  }
}

__global__ void ed_update(float* __restrict__ ed, const float* __restrict__ agg,
                          const float* __restrict__ mu_e, const float* __restrict__ rs_e)
{
  long long idx = (long long)blockIdx.x * 256 + threadIdx.x;
  if (idx >= (long long)B * E * C) return;
  int e = (int)((idx / C) % E);
  float v = (agg[idx] - mu_e[e]) * rs_e[e];
  ed[idx] += fmaxf(v, 0.f);
}

// ------- sigmoid -> softmax over j -> msg, pre = U + msg; block per (b,i) -------
__global__ __launch_bounds__(256)
void msg_k(const float* __restrict__ ed, const float* __restrict__ ABUV,
           float* __restrict__ pre)
{
  const int bid = blockIdx.x;
  const int b = bid / N, i = bid % N;
  const int tid = threadIdx.x;
  for (int c = tid; c < C; c += 256) {
    float sv[N];
    float m = -1e30f;
#pragma unroll
    for (int jn = 0; jn < N; ++jn) {
      float xx = ed[((long long)b * E + i * N + jn) * C + c];
      float sg = 1.f / (1.f + __expf(-xx));
      sv[jn] = sg;
      m = fmaxf(m, sg);
    }
    float sum = 0.f;
#pragma unroll
    for (int jn = 0; jn < N; ++jn) { float ev = __expf(sv[jn] - m); sv[jn] = ev; sum += ev; }
    float acc = 0.f;
#pragma unroll
    for (int jn = 0; jn < N; ++jn)
      acc = fmaf(sv[jn], ABUV[(long long)(b * N + jn) * 2048 + 1536 + c], acc);
    acc /= (sum * (float)N);
    pre[(b * N + i) * C + c] = ABUV[(long long)(b * N + i) * 2048 + 1024 + c] + acc;
  }
}

__global__ __launch_bounds__(256)
void node_stats(const float* __restrict__ pre, float* __restrict__ mu_i,
                float* __restrict__ rs_i)
{
  const int i = blockIdx.x;
  const int tid = threadIdx.x;
  float s = 0.f, q = 0.f;
  for (int idx = tid; idx < B * C; idx += 256) {
    int b = idx >> 9, c = idx & 511;
    float v = pre[(b * N + i) * C + c];
    s += v; q += v * v;
  }
  for (int off = 32; off; off >>= 1) { s += __shfl_down(s, off); q += __shfl_down(q, off); }
  __shared__ float r0[4], r1[4];
  int wid = tid >> 6, lane = tid & 63;
  if (lane == 0) { r0[wid] = s; r1[wid] = q; }
  __syncthreads();
  if (tid == 0) {
    float ss = r0[0] + r0[1] + r0[2] + r0[3];
    float qq = r1[0] + r1[1] + r1[2] + r1[3];
    float m = ss / (float)(B * C);
    mu_i[i] = m;
    rs_i[i] = rsqrtf(qq / (float)(B * C) - m * m + BN_EPS);
  }
}

__global__ void xv_update(float* __restrict__ xv, const float* __restrict__ pre,
                          const float* __restrict__ mu_i, const float* __restrict__ rs_i)
{
  long long idx = (long long)blockIdx.x * 256 + threadIdx.x;
  if (idx >= (long long)B * N * C) return;
  int i = (int)((idx / C) % N);
  float v = xv[idx] + (pre[idx] - mu_i[i]) * rs_i[i];
  xv[idx] = fmaxf(v, 0.f);
}

// ---------------- cosine classifier ----------------
__global__ __launch_bounds__(256)
void cl_k(const float* __restrict__ xv, const float* __restrict__ sc,
          float* __restrict__ out)
{
  const int bid = blockIdx.x;
  const int b = bid / N, i = bid % N;
  const int tid = threadIdx.x;
  float sxx = 0.f, sss = 0.f, sxs = 0.f;
  for (int c = tid; c < C; c += 256) {
    float xvv = xv[(long long)(b * N + i) * C + c];
    float scv = fmaxf(sc[i * C + c], 0.f);
    sxx += xvv * xvv; sss += scv * scv; sxs += xvv * scv;
  }
  for (int off = 32; off; off >>= 1) {
    sxx += __shfl_down(sxx, off);
    sss += __shfl_down(sss, off);
    sxs += __shfl_down(sxs, off);
  }
  __shared__ float r0[4], r1[4], r2[4];
  int wid = tid >> 6, lane = tid & 63;
  if (lane == 0) { r0[wid] = sxx; r1[wid] = sss; r2[wid] = sxs; }
  __syncthreads();
  if (tid == 0) {
    float a = r0[0] + r0[1] + r0[2] + r0[3];
    float s = r1[0] + r1[1] + r1[2] + r1[3];
    float p = r2[0] + r2[1] + r2[2] + r2[3];
    float nx = fmaxf(sqrtf(a), 1e-12f);
    float ns = fmaxf(sqrtf(s), 1e-12f);
    out[b * N + i] = p / (nx * ns);
  }
}

// ---------------- cl_edge = ed @ efc_w + efc_b ----------------
__global__ __launch_bounds__(64)
void cledge_k(const float* __restrict__ ed, const float* __restrict__ w,
              const float* __restrict__ bias, float* __restrict__ out)
{
  const int bid = blockIdx.x;  // b*E + e
  const int lane = threadIdx.x;
  float a0 = 0, a1 = 0, a2 = 0, a3 = 0;
  for (int c = lane; c < C; c += 64) {
    float v = ed[(long long)bid * C + c];
    a0 = fmaf(v, w[c * 4 + 0], a0);
    a1 = fmaf(v, w[c * 4 + 1], a1);
    a2 = fmaf(v, w[c * 4 + 2], a2);
    a3 = fmaf(v, w[c * 4 + 3], a3);
  }
  for (int off = 32; off; off >>= 1) {
    a0 += __shfl_down(a0, off);
    a1 += __shfl_down(a1, off);
    a2 += __shfl_down(a2, off);
    a3 += __shfl_down(a3, off);
  }
  if (lane == 0) {
    out[B * N + bid * 4 + 0] = a0 + bias[0];
    out[B * N + bid * 4 + 1] = a1 + bias[1];
    out[B * N + bid * 4 + 2] = a2 + bias[2];
    out[B * N + bid * 4 + 3] = a3 + bias[3];
  }
}

} // namespace

extern "C" void kernel_launch(void* const* d_in, const int* in_sizes, int n_in,
                              void* d_out, int out_size, void* d_ws, size_t ws_size,
                              hipStream_t stream)
{
  (void)in_sizes; (void)n_in; (void)out_size; (void)ws_size;
  const float* x      = (const float*)d_in[0];
  const float* Wc     = (const float*)d_in[1];
  const float* bc     = (const float*)d_in[2];
  const float* fam_wq = (const float*)d_in[3];
  const float* fam_bq = (const float*)d_in[4];
  const float* fam_wk = (const float*)d_in[5];
  const float* fam_bk = (const float*)d_in[6];
  const float* fam_wv = (const float*)d_in[7];
  const float* fam_bv = (const float*)d_in[8];
  const float* arm_wq = (const float*)d_in[9];
  const float* arm_bq = (const float*)d_in[10];
  const float* arm_wk = (const float*)d_in[11];
  const float* arm_bk = (const float*)d_in[12];
  const float* arm_wv = (const float*)d_in[13];
  const float* arm_bv = (const float*)d_in[14];
  const float* ep_w   = (const float*)d_in[15];
  const float* ep_b   = (const float*)d_in[16];
  const float* gw[10] = {
    (const float*)d_in[17], (const float*)d_in[18], (const float*)d_in[19],
    (const float*)d_in[20], (const float*)d_in[21],
    (const float*)d_in[22], (const float*)d_in[23], (const float*)d_in[24],
    (const float*)d_in[25], (const float*)d_in[26]};
  const float* sc     = (const float*)d_in[27];
  const float* efc_w  = (const float*)d_in[28];
  const float* efc_b  = (const float*)d_in[29];
  float* out = (float*)d_out;

  char* wsb = (char*)d_ws;
  size_t off = 0;
  auto allocf = [&](size_t n) { float* p = (float*)(wsb + off); off += ((n * 4 + 255) / 256) * 256; return p; };
  auto allocu = [&](size_t n) { unsigned short* p = (unsigned short*)(wsb + off); off += ((n * 2 + 255) / 256) * 256; return p; };

  // region1: h_t early; reused for S1/fe/EW/agg after fu_fv
  float* region1 = allocf(2408448);
  float* h_t = region1;
  float* S1  = region1;
  float* fe  = region1 + 589824;
  float* EW  = region1 + 1179648;
  float* agg = region1 + 1769472;
  // region2: f_u early; reused for qf/kf after q1 GEMM
  float* region2 = allocf(2408448);
  float* f_u = region2;
  float* qf  = region2;
  float* kf  = region2 + 1204224;

  float* mu_h = allocf(6144);
  float* rs_h = allocf(6144);
  float* f_v  = allocf(49152);
  float* q1   = allocf(1204224);
  float* kx   = allocf(100352);
  float* vx   = allocf(200704);
  float* feat = allocf(2408448);
  float* vfe  = allocf(2408448);
  float* W2   = allocf(262144);
  float* b2   = allocf(512);
  float* eS   = allocf(2304);
  float* me   = allocf(144);
  float* rve  = allocf(144);
  float* mask = allocf(1152);
  float* ABUV = allocf(196608);
  float* pre  = allocf(49152);
  float* mu_e = allocf(144);
  float* rs_e = allocf(144);
  float* mu_i = allocf(16);
  float* rs_i = allocf(16);

  unsigned short* Wct    = allocu(3145728);
  unsigned short* famqt  = allocu(131072);
  unsigned short* famkt  = allocu(131072);
  unsigned short* famvt  = allocu(262144);
  unsigned short* armqt  = allocu(131072);
  unsigned short* armkt  = allocu(131072);
  unsigned short* epwt   = allocu(262144);
  unsigned short* W2t    = allocu(262144);
  unsigned short* ABUVt0 = allocu(1048576);
  unsigned short* ABUVt1 = allocu(1048576);
  unsigned short* wet0   = allocu(262144);
  unsigned short* wet1   = allocu(262144);

  dim3 blk(256);

  // -------- weight transpose+cast (28 jobs) --------
  TCJobs tj{};
  int jn = 0;
  for (int n = 0; n < 12; ++n) { tj.src[jn] = Wc + (size_t)n * C * C; tj.dst[jn] = Wct + (size_t)n * C * C; tj.nn[jn] = C; ++jn; }
  tj.src[jn] = fam_wq; tj.dst[jn] = famqt; tj.nn[jn] = H; ++jn;
  tj.src[jn] = fam_wk; tj.dst[jn] = famkt; tj.nn[jn] = H; ++jn;
  tj.src[jn] = fam_wv; tj.dst[jn] = famvt; tj.nn[jn] = C; ++jn;
  tj.src[jn] = arm_wq; tj.dst[jn] = armqt; tj.nn[jn] = H; ++jn;
  tj.src[jn] = arm_wk; tj.dst[jn] = armkt; tj.nn[jn] = H; ++jn;
  tj.src[jn] = ep_w;   tj.dst[jn] = epwt;  tj.nn[jn] = C; ++jn;
  tj.src[jn] = gw[2];  tj.dst[jn] = wet0;  tj.nn[jn] = C; ++jn;   // we1
  tj.src[jn] = gw[7];  tj.dst[jn] = wet1;  tj.nn[jn] = C; ++jn;   // we2
  tj.src[jn] = gw[0];  tj.dst[jn] = ABUVt0;                 tj.nn[jn] = C; ++jn; // wa1
  tj.src[jn] = gw[1];  tj.dst[jn] = ABUVt0 + 1 * C * C;     tj.nn[jn] = C; ++jn; // wb1
  tj.src[jn] = gw[3];  tj.dst[jn] = ABUVt0 + 2 * C * C;     tj.nn[jn] = C; ++jn; // wu1
  tj.src[jn] = gw[4];  tj.dst[jn] = ABUVt0 + 3 * C * C;     tj.nn[jn] = C; ++jn; // wv1
  tj.src[jn] = gw[5];  tj.dst[jn] = ABUVt1;                 tj.nn[jn] = C; ++jn; // wa2
  tj.src[jn] = gw[6];  tj.dst[jn] = ABUVt1 + 1 * C * C;     tj.nn[jn] = C; ++jn; // wb2
  tj.src[jn] = gw[8];  tj.dst[jn] = ABUVt1 + 2 * C * C;     tj.nn[jn] = C; ++jn; // wu2
  tj.src[jn] = gw[9];  tj.dst[jn] = ABUVt1 + 3 * C * C;     tj.nn[jn] = C; ++jn; // wv2
  tcast_k<<<dim3(16, 16, 28), blk, 0, stream>>>(tj);

  b2full_k<<<dim3(2), blk, 0, stream>>>(arm_bv, ep_w, ep_b, b2);

  // h[n] = x @ Wc[n] + bc[n]
  gemm_mfma<<<dim3(7, 8, 12), blk, 0, stream>>>(x, Wct, bc, h_t, M_BD, C, C,
      0LL, (long long)C * C, (long long)C, (long long)M_BD * C);
  bn_stats_nc<<<dim3((N * C + 255) / 256), blk, 0, stream>>>(h_t, mu_h, rs_h);
  fu_fv<<<dim3(B * N, 2), blk, 0, stream>>>(h_t, mu_h, rs_h, f_u, f_v);

  // fam projections + attention
  gemm_mfma<<<dim3(74, 4, 1), blk, 0, stream>>>(f_u, famqt, fam_bq, q1, M_BND, H, C, 0, 0, 0, 0);
  gemm_mfma<<<dim3(7, 4, 1),  blk, 0, stream>>>(x, famkt, fam_bk, kx, M_BD, H, C, 0, 0, 0, 0);
  gemm_mfma<<<dim3(7, 8, 1),  blk, 0, stream>>>(x, famvt, fam_bv, vx, M_BD, C, C, 0, 0, 0, 0);
  attn_fam<<<dim3(B * N, 2), blk, 0, stream>>>(q1, kx, vx, feat);

  // arm projections; ep_w folded through v (softmax rows sum to 1)
  gemm_mfma<<<dim3(74, 4, 1), blk, 0, stream>>>(feat, armqt, arm_bq, qf, M_BND, H, C, 0, 0, 0, 0);
  gemm_mfma<<<dim3(74, 4, 1), blk, 0, stream>>>(feat, armkt, arm_bk, kf, M_BND, H, C, 0, 0, 0, 0);
  gemm_mfma<<<dim3(8, 8, 1),  blk, 0, stream>>>(arm_wv, epwt, nullptr, W2, C, C, C, 0, 0, 0, 0);
  {
    TCJobs tj2{};
    tj2.src[0] = W2; tj2.dst[0] = W2t; tj2.nn[0] = C;
    tcast_k<<<dim3(16, 16, 1), blk, 0, stream>>>(tj2);
  }
  gemm_mfma<<<dim3(74, 8, 1), blk, 0, stream>>>(feat, W2t, b2, vfe, M_BND, C, C, 0, 0, 0, 0);

  // per-edge attention + fused BN-stat accumulation
  attn_edge<<<dim3(B * E), blk, 0, stream>>>(qf, kf, vfe, S1, eS);
  edge_me<<<dim3(1), blk, 0, stream>>>(eS, me, rve);
  mask_k<<<dim3(B), blk, 0, stream>>>(f_v, mask);
  fe_k<<<dim3((B * E * C + 255) / 256), blk, 0, stream>>>(S1, me, rve, mask, fe);

  // two GNN layers
  for (int L = 0; L < 2; ++L) {
    const unsigned short* ABUVt = L ? ABUVt1 : ABUVt0;
    const unsigned short* wet   = L ? wet1 : wet0;
    gemm_mfma<<<dim3(2, 32, 1), blk, 0, stream>>>(f_v, ABUVt, nullptr, ABUV, B * N, 2048, C, 0, 0, 0, 0);
    gemm_mfma<<<dim3(18, 8, 1), blk, 0, stream>>>(fe, wet, nullptr, EW, B * E, C, C, 0, 0, 0, 0);
    agg_stats<<<dim3(E), blk, 0, stream>>>(ABUV, EW, agg, mu_e, rs_e);
    ed_update<<<dim3((B * E * C + 255) / 256), blk, 0, stream>>>(fe, agg, mu_e, rs_e);
    msg_k<<<dim3(B * N), blk, 0, stream>>>(fe, ABUV, pre);
    node_stats<<<dim3(N), blk, 0, stream>>>(pre, mu_i, rs_i);
    xv_update<<<dim3((B * N * C + 255) / 256), blk, 0, stream>>>(f_v, pre, mu_i, rs_i);
  }

  cl_k<<<dim3(B * N), blk, 0, stream>>>(f_v, sc, out);
  cledge_k<<<dim3(B * E), dim3(64), 0, stream>>>(fe, efc_w, efc_b, out);
}

// Round 3
// 363.781 us; speedup vs baseline: 6.1441x; 1.2098x over previous
//
#include <hip/hip_runtime.h>
#include <math.h>

namespace {

constexpr int B = 8, D = 49, C = 512, N = 12, H = 256, E = 144;
constexpr int M_BD  = B * D;        // 392
constexpr int M_BND = B * N * D;    // 4704
constexpr float BN_EPS = 1e-5f;
constexpr float ATT_SCALE = 0.0625f; // (C/2)^-0.5

typedef __attribute__((ext_vector_type(4))) float  floatx4;
typedef __attribute__((ext_vector_type(8))) short  shortx8;

__device__ inline unsigned short f2bf(float f) {
  unsigned u = __float_as_uint(f);
  return (unsigned short)((u + 0x7fffu + ((u >> 16) & 1u)) >> 16);
}

// ---------------- transpose+cast fp32 [K=512][Nn] -> bf16 [Nn][512] ----------------
struct TCJobs {
  const float* src[28];
  unsigned short* dst[28];
  int nn[28];
};

__global__ __launch_bounds__(256)
void tcast_k(TCJobs jobs)
{
  const int z = blockIdx.z;
  const float* src = jobs.src[z];
  unsigned short* dst = jobs.dst[z];
  const int Nn = jobs.nn[z];
  const int tx = blockIdx.x, ty = blockIdx.y;
  if (tx * 32 >= Nn) return;
  __shared__ float t[32][33];
  const int tid = threadIdx.x;
  const int lr = tid >> 5, lc = tid & 31;
#pragma unroll
  for (int p = 0; p < 4; ++p) {
    int k = ty * 32 + p * 8 + lr;
    t[p * 8 + lr][lc] = src[(long long)k * Nn + tx * 32 + lc];
  }
  __syncthreads();
#pragma unroll
  for (int p = 0; p < 4; ++p) {
    int n = tx * 32 + p * 8 + lr;
    dst[(long long)n * 512 + ty * 32 + lc] = f2bf(t[lc][p * 8 + lr]);
  }
}

// ---------------- bf16 MFMA GEMM: A fp32 [M][K], Bt bf16 [Nn][K] ----------------
// Optional fp32 out (Co) and/or bf16 out (Cb). 64x64 tile, BK=64, 4 waves.
__global__ __launch_bounds__(256)
void gemm_mfma(const float* __restrict__ A, const unsigned short* __restrict__ Bt,
               const float* __restrict__ bias, float* __restrict__ Co,
               unsigned short* __restrict__ Cb,
               int M, int Nn, int K,
               long long sA, long long sB, long long sBias, long long sC)
{
  const int z = blockIdx.z;
  A  += z * sA; Bt += z * sB;
  if (Co) Co += z * sC;
  if (Cb) Cb += z * sC;
  const float* bp = bias ? bias + z * sBias : nullptr;

  __shared__ short As[64 * 72];
  __shared__ short Bs[64 * 72];

  const int tid = threadIdx.x;
  const int row0 = blockIdx.x * 64, col0 = blockIdx.y * 64;
  const int wid = tid >> 6, lane = tid & 63;
  const int wr = wid >> 1, wc = wid & 1;
  const int lr = lane & 15, lg = lane >> 4;

  floatx4 acc00 = {0.f,0.f,0.f,0.f}, acc01 = {0.f,0.f,0.f,0.f};
  floatx4 acc10 = {0.f,0.f,0.f,0.f}, acc11 = {0.f,0.f,0.f,0.f};

  const int r = tid >> 2, seg = tid & 3;
  const int gr = row0 + r, gn = col0 + r;
  const float* apB = A + (long long)gr * K + seg * 16;
  const unsigned short* bpB = Bt + (long long)gn * K + seg * 16;
  short* aw = &As[r * 72 + seg * 16];
  short* bw = &Bs[r * 72 + seg * 16];

  for (int k0 = 0; k0 < K; k0 += 64) {
    float4 fa0, fa1, fa2, fa3;
    if (gr < M) {
      const float4* ap = reinterpret_cast<const float4*>(apB + k0);
      fa0 = ap[0]; fa1 = ap[1]; fa2 = ap[2]; fa3 = ap[3];
    } else {
      fa0 = make_float4(0.f,0.f,0.f,0.f); fa1 = fa0; fa2 = fa0; fa3 = fa0;
    }
    shortx8 w0, w1;
    w0[0]=(short)f2bf(fa0.x); w0[1]=(short)f2bf(fa0.y); w0[2]=(short)f2bf(fa0.z); w0[3]=(short)f2bf(fa0.w);
    w0[4]=(short)f2bf(fa1.x); w0[5]=(short)f2bf(fa1.y); w0[6]=(short)f2bf(fa1.z); w0[7]=(short)f2bf(fa1.w);
    w1[0]=(short)f2bf(fa2.x); w1[1]=(short)f2bf(fa2.y); w1[2]=(short)f2bf(fa2.z); w1[3]=(short)f2bf(fa2.w);
    w1[4]=(short)f2bf(fa3.x); w1[5]=(short)f2bf(fa3.y); w1[6]=(short)f2bf(fa3.z); w1[7]=(short)f2bf(fa3.w);
    shortx8 b0v = *reinterpret_cast<const shortx8*>(bpB + k0);
    shortx8 b1v = *reinterpret_cast<const shortx8*>(bpB + k0 + 8);

    __syncthreads();
    *reinterpret_cast<shortx8*>(aw)     = w0;
    *reinterpret_cast<shortx8*>(aw + 8) = w1;
    *reinterpret_cast<shortx8*>(bw)     = b0v;
    *reinterpret_cast<shortx8*>(bw + 8) = b1v;
    __syncthreads();

#pragma unroll
    for (int kt = 0; kt < 2; ++kt) {
      shortx8 a0 = *reinterpret_cast<const shortx8*>(&As[(wr*32      + lr) * 72 + kt*32 + lg*8]);
      shortx8 a1 = *reinterpret_cast<const shortx8*>(&As[(wr*32 + 16 + lr) * 72 + kt*32 + lg*8]);
      shortx8 bb0 = *reinterpret_cast<const shortx8*>(&Bs[(wc*32      + lr) * 72 + kt*32 + lg*8]);
      shortx8 bb1 = *reinterpret_cast<const shortx8*>(&Bs[(wc*32 + 16 + lr) * 72 + kt*32 + lg*8]);
      acc00 = __builtin_amdgcn_mfma_f32_16x16x32_bf16(a0, bb0, acc00, 0, 0, 0);
      acc01 = __builtin_amdgcn_mfma_f32_16x16x32_bf16(a0, bb1, acc01, 0, 0, 0);
      acc10 = __builtin_amdgcn_mfma_f32_16x16x32_bf16(a1, bb0, acc10, 0, 0, 0);
      acc11 = __builtin_amdgcn_mfma_f32_16x16x32_bf16(a1, bb1, acc11, 0, 0, 0);
    }
  }

  const int colA = col0 + wc * 32 + lr;
  const int colB = colA + 16;
  const bool okA = colA < Nn, okB = colB < Nn;
  const float biasA = (bp && okA) ? bp[colA] : 0.f;
  const float biasB = (bp && okB) ? bp[colB] : 0.f;
  const int rb0 = row0 + wr * 32 + lg * 4;
  const int rb1 = rb0 + 16;
#pragma unroll
  for (int jj = 0; jj < 4; ++jj) {
    int ra = rb0 + jj, rb = rb1 + jj;
    float v00 = acc00[jj] + biasA, v01 = acc01[jj] + biasB;
    float v10 = acc10[jj] + biasA, v11 = acc11[jj] + biasB;
    if (ra < M) {
      if (Co) { if (okA) Co[(long long)ra * Nn + colA] = v00;
                if (okB) Co[(long long)ra * Nn + colB] = v01; }
      if (Cb) { if (okA) Cb[(long long)ra * Nn + colA] = f2bf(v00);
                if (okB) Cb[(long long)ra * Nn + colB] = f2bf(v01); }
    }
    if (rb < M) {
      if (Co) { if (okA) Co[(long long)rb * Nn + colA] = v10;
                if (okB) Co[(long long)rb * Nn + colB] = v11; }
      if (Cb) { if (okA) Cb[(long long)rb * Nn + colA] = f2bf(v10);
                if (okB) Cb[(long long)rb * Nn + colB] = f2bf(v11); }
    }
  }
}

// ---------------- BN stats per (n,c): 8 row-slices then reduce ----------------
__global__ __launch_bounds__(256)
void bn_stats_part(const float* __restrict__ h, float* __restrict__ ps,
                   float* __restrict__ pq)
{
  int idx = blockIdx.x * 256 + threadIdx.x;      // 0..6143 (n*C+c)
  int n = idx >> 9, c = idx & 511;
  int slice = blockIdx.y;                        // 0..7, 49 rows each
  const float* p = h + (long long)n * M_BD * C + (long long)slice * 49 * C + c;
  float s = 0.f, q = 0.f;
  for (int rr = 0; rr < 49; ++rr) { float v = p[(long long)rr * C]; s += v; q += v * v; }
  ps[slice * (N * C) + idx] = s;
  pq[slice * (N * C) + idx] = q;
}

__global__ __launch_bounds__(256)
void bn_stats_final(const float* __restrict__ ps, const float* __restrict__ pq,
                    float* __restrict__ mu, float* __restrict__ rs)
{
  int idx = blockIdx.x * 256 + threadIdx.x;
  float s = 0.f, q = 0.f;
#pragma unroll
  for (int sl = 0; sl < 8; ++sl) { s += ps[sl * (N * C) + idx]; q += pq[sl * (N * C) + idx]; }
  float m = s / (float)M_BD;
  mu[idx] = m;
  rs[idx] = rsqrtf(q / (float)M_BD - m * m + BN_EPS);
}

// ---------------- f_u = relu(norm(h)), f_v = mean_d f_u ; grid (B*N, 2) ----------------
__global__ __launch_bounds__(256)
void fu_fv(const float* __restrict__ h, const float* __restrict__ mu,
           const float* __restrict__ rs, float* __restrict__ fu,
           float* __restrict__ fv)
{
  const int bid = blockIdx.x;           // b*N+n
  const int b = bid / N, n = bid % N;
  const int c = blockIdx.y * 256 + threadIdx.x;
  float m = mu[n * C + c], rv = rs[n * C + c];
  float acc = 0.f;
  for (int d = 0; d < D; ++d) {
    float v = h[((long long)n * M_BD + b * D + d) * C + c];
    v = fmaxf((v - m) * rv, 0.f);
    fu[((long long)bid * D + d) * C + c] = v;
    acc += v;
  }
  fv[(long long)bid * C + c] = acc * (1.0f / (float)D);
}

// PV over CNT rows starting at `off`; one c-column per thread.
template<int CNT>
__device__ inline void pv_half(const float (*__restrict__ s_lds)[52],
                               const float* __restrict__ Vp, int off, int cg,
                               float* __restrict__ O)
{
  float t[CNT];
#pragma unroll
  for (int ii = 0; ii < CNT; ++ii) t[ii] = 0.f;
  for (int djc = 0; djc < 48; djc += 4) {
    float v0 = Vp[(djc + 0) * C + cg];
    float v1 = Vp[(djc + 1) * C + cg];
    float v2 = Vp[(djc + 2) * C + cg];
    float v3 = Vp[(djc + 3) * C + cg];
#pragma unroll
    for (int ii = 0; ii < CNT; ++ii) {
      const float4 s4 = *reinterpret_cast<const float4*>(&s_lds[off + ii][djc]);
      t[ii] = fmaf(s4.x, v0, t[ii]); t[ii] = fmaf(s4.y, v1, t[ii]);
      t[ii] = fmaf(s4.z, v2, t[ii]); t[ii] = fmaf(s4.w, v3, t[ii]);
    }
  }
  {
    float v = Vp[48 * C + cg];
#pragma unroll
    for (int ii = 0; ii < CNT; ++ii) t[ii] = fmaf(s_lds[off + ii][48], v, t[ii]);
  }
#pragma unroll
  for (int ii = 0; ii < CNT; ++ii) O[(long long)(off + ii) * C + cg] = t[ii];
}

// ---------------- fam: softmax(Sf block) then PV; one block per (b,n) ----------------
__global__ __launch_bounds__(256)
void fam_finish(const float* __restrict__ Sf, const float* __restrict__ Vg,
                float* __restrict__ Og)
{
  const int bid = blockIdx.x;
  const int b = bid / N;
  const float* Sp = Sf + (long long)bid * 2401;   // [49][49] contiguous
  const float* Vp = Vg + (long long)b * D * C;
  float* O = Og + (long long)bid * D * C;
  __shared__ float a[D][52];
  const int tid = threadIdx.x;
  for (int idx = tid; idx < D * 52; idx += 256) {
    int rr = idx / 52, cc = idx % 52;
    a[rr][cc] = (cc < D) ? Sp[rr * 49 + cc] * ATT_SCALE : 0.f;
  }
  __syncthreads();
  if (tid < D) {
    float m = -1e30f;
    for (int jj = 0; jj < D; ++jj) m = fmaxf(m, a[tid][jj]);
    float s = 0.f;
    for (int jj = 0; jj < D; ++jj) { float ev = __expf(a[tid][jj] - m); a[tid][jj] = ev; s += ev; }
    float inv = 1.f / s;
    for (int jj = 0; jj < D; ++jj) a[tid][jj] *= inv;
  }
  __syncthreads();
  for (int cc = 0; cc < C; cc += 256) {
    int cg = cc + tid;
    pv_half<25>(a, Vp, 0,  cg, O);
    pv_half<24>(a, Vp, 25, cg, O);
  }
}

// ---------------- edge finish: softmax + colsum@V + a·(A@G)·a ----------------
__global__ __launch_bounds__(256)
void edge_finish(const float* __restrict__ Sc, const float* __restrict__ G,
                 const float* __restrict__ vfe, float* __restrict__ S1,
                 float* __restrict__ eS)
{
  const int bid = blockIdx.x;           // b*E + e
  const int b = bid / E, e = bid % E;
  const int i = e / N, j = e % N;
  const float* Scb = Sc + (long long)b * 588 * 588 + (long long)(j * 49) * 588 + i * 49;
  const float* Gp  = G + (long long)(b * N + i) * 2401;
  const float* Vp  = vfe + (long long)(b * N + i) * D * C;

  __shared__ float a[52][53];
  __shared__ float g[D][52];
  __shared__ float ws[D];
  __shared__ float r0[4], r1[4];
  const int tid = threadIdx.x;

  for (int idx = tid; idx < 52 * 53; idx += 256) {
    int rr = idx / 53, cc = idx % 53;
    a[rr][cc] = (rr < D && cc < D) ? Scb[rr * 588 + cc] * ATT_SCALE : 0.f;
  }
  for (int idx = tid; idx < D * 52; idx += 256) {
    int rr = idx / 52, cc = idx % 52;
    g[rr][cc] = (cc < D) ? Gp[rr * 49 + cc] : 0.f;
  }
  __syncthreads();
  // softmax rows
  if (tid < D) {
    float m = -1e30f;
    for (int jj = 0; jj < D; ++jj) m = fmaxf(m, a[tid][jj]);
    float s = 0.f;
    for (int jj = 0; jj < D; ++jj) { float ev = __expf(a[tid][jj] - m); a[tid][jj] = ev; s += ev; }
    float inv = 1.f / s;
    for (int jj = 0; jj < D; ++jj) a[tid][jj] *= inv;
  }
  __syncthreads();
  // column sums of A
  if (tid < D) {
    float s = 0.f;
    for (int qr = 0; qr < D; ++qr) s += a[qr][tid];
    ws[tid] = s;
  }
  __syncthreads();

  // st2 = sum_{di} a[di] G a[di]^T  via AG register tile
  float st2 = 0.f;
  if (tid < 169) {
    const int qr0 = (tid % 13) * 4, gj0 = (tid / 13) * 4;
    float AG[4][4];
#pragma unroll
    for (int ii = 0; ii < 4; ++ii)
#pragma unroll
      for (int jj = 0; jj < 4; ++jj) AG[ii][jj] = 0.f;
    for (int dk = 0; dk < D; ++dk) {
      float a0 = a[qr0 + 0][dk], a1 = a[qr0 + 1][dk];
      float a2 = a[qr0 + 2][dk], a3 = a[qr0 + 3][dk];
      const float4 g4 = *reinterpret_cast<const float4*>(&g[dk][gj0]);
      AG[0][0]=fmaf(a0,g4.x,AG[0][0]); AG[0][1]=fmaf(a0,g4.y,AG[0][1]);
      AG[0][2]=fmaf(a0,g4.z,AG[0][2]); AG[0][3]=fmaf(a0,g4.w,AG[0][3]);
      AG[1][0]=fmaf(a1,g4.x,AG[1][0]); AG[1][1]=fmaf(a1,g4.y,AG[1][1]);
      AG[1][2]=fmaf(a1,g4.z,AG[1][2]); AG[1][3]=fmaf(a1,g4.w,AG[1][3]);
      AG[2][0]=fmaf(a2,g4.x,AG[2][0]); AG[2][1]=fmaf(a2,g4.y,AG[2][1]);
      AG[2][2]=fmaf(a2,g4.z,AG[2][2]); AG[2][3]=fmaf(a2,g4.w,AG[2][3]);
      AG[3][0]=fmaf(a3,g4.x,AG[3][0]); AG[3][1]=fmaf(a3,g4.y,AG[3][1]);
      AG[3][2]=fmaf(a3,g4.z,AG[3][2]); AG[3][3]=fmaf(a3,g4.w,AG[3][3]);
    }
#pragma unroll
    for (int ii = 0; ii < 4; ++ii)
#pragma unroll
      for (int jj = 0; jj < 4; ++jj)
        st2 = fmaf(AG[ii][jj], a[qr0 + ii][gj0 + jj], st2);
  }

  // S1 = colsum(A) @ V, st = sum of S1
  float st = 0.f;
#pragma unroll
  for (int cc = 0; cc < C; cc += 256) {
    int cg = cc + tid;
    float s1 = 0.f;
    for (int dk = 0; dk < D; ++dk) s1 = fmaf(ws[dk], Vp[dk * C + cg], s1);
    S1[(long long)bid * C + cg] = s1;
    st += s1;
  }

  for (int off = 32; off; off >>= 1) { st += __shfl_down(st, off); st2 += __shfl_down(st2, off); }
  int wid = tid >> 6, lane = tid & 63;
  if (lane == 0) { r0[wid] = st; r1[wid] = st2; }
  __syncthreads();
  if (tid == 0) {
    eS[bid * 2 + 0] = r0[0] + r0[1] + r0[2] + r0[3];
    eS[bid * 2 + 1] = r1[0] + r1[1] + r1[2] + r1[3];
  }
}

// ---------------- b2 = arm_bv @ ep_w + ep_b ----------------
__global__ void b2full_k(const float* __restrict__ bv, const float* __restrict__ epw,
                         const float* __restrict__ epb, float* __restrict__ b2)
{
  int c = blockIdx.x * blockDim.x + threadIdx.x;
  if (c >= C) return;
  float s = epb[c];
  for (int k = 0; k < C; ++k) s = fmaf(bv[k], epw[k * C + c], s);
  b2[c] = s;
}

// ---------------- per-e BN constants for f_e ----------------
__global__ void edge_me(const float* __restrict__ eS, float* __restrict__ me,
                        float* __restrict__ rve)
{
  int e = blockIdx.x * blockDim.x + threadIdx.x;
  if (e >= E) return;
  float s = 0.f, q = 0.f;
  for (int b = 0; b < B; ++b) { s += eS[(b * E + e) * 2]; q += eS[(b * E + e) * 2 + 1]; }
  const float inv = 1.f / (float)(B * D * C);
  float m = s * inv;
  me[e] = m;
  rve[e] = rsqrtf(q * inv - m * m + BN_EPS);
}

// ---------------- cosine-similarity mask, one block per b ----------------
__global__ __launch_bounds__(256)
void mask_k(const float* __restrict__ fv, float* __restrict__ mask)
{
  const int b = blockIdx.x;
  __shared__ float fl[N][C];
  __shared__ float adj[N][N];
  __shared__ float nrm[N];
  __shared__ float dis[N];
  const int tid = threadIdx.x;
  for (int idx = tid; idx < N * C; idx += 256)
    fl[idx / C][idx % C] = fv[(long long)b * N * C + idx];
  __syncthreads();
  if (tid < N * N) {
    int i = tid / N, j = tid % N;
    float s = 0.f;
    for (int k = 0; k < C; ++k) s += fl[i][k] * fl[j][k];
    adj[i][j] = s;
  }
  __syncthreads();
  if (tid < N) nrm[tid] = fmaxf(sqrtf(adj[tid][tid]), 1e-12f);
  __syncthreads();
  if (tid < N * N) {
    int i = tid / N, j = tid % N;
    adj[i][j] = adj[i][j] / (nrm[i] * nrm[j]);
  }
  __syncthreads();
  if (tid < N) {
    float s = 0.f;
    for (int j = 0; j < N; ++j) s += adj[tid][j];
    dis[tid] = rsqrtf(s);
  }
  __syncthreads();
  if (tid < N * N) {
    int i = tid / N, j = tid % N;
    mask[b * E + tid] = adj[i][j] * dis[i] * dis[j];
  }
}

// ---------------- f_e = (S1/D - me)*rve * mask ----------------
__global__ void fe_k(const float* __restrict__ S1, const float* __restrict__ me,
                     const float* __restrict__ rve, const float* __restrict__ mask,
                     float* __restrict__ fe)
{
  long long idx = (long long)blockIdx.x * 256 + threadIdx.x;
  if (idx >= (long long)B * E * C) return;
  long long be = idx / C;
  int e = (int)(be % E);
  fe[idx] = (S1[idx] * (1.0f / (float)D) - me[e]) * rve[e] * mask[be];
}

// ---------------- GNN: agg = A[i] + B[j] + EW[e], BN stats per e ----------------
__global__ __launch_bounds__(256)
void agg_stats(const float* __restrict__ ABUV, const float* __restrict__ EW,
               float* __restrict__ agg, float* __restrict__ mu_e, float* __restrict__ rs_e)
{
  const int e = blockIdx.x;
  const int i = e / N, j = e % N;
  const int tid = threadIdx.x;
  float s = 0.f, q = 0.f;
  for (int idx = tid; idx < B * C; idx += 256) {
    int b = idx >> 9, c = idx & 511;
    float v = ABUV[(long long)(b * N + i) * 2048 + c]
            + ABUV[(long long)(b * N + j) * 2048 + 512 + c]
            + EW[((long long)b * E + e) * C + c];
    agg[((long long)b * E + e) * C + c] = v;
    s += v; q += v * v;
  }
  for (int off = 32; off; off >>= 1) { s += __shfl_down(s, off); q += __shfl_down(q, off); }
  __shared__ float r0[4], r1[4];
  int wid = tid >> 6, lane = tid & 63;
  if (lane == 0) { r0[wid] = s; r1[wid] = q; }
  __syncthreads();
  if (tid == 0) {
    float ss = r0[0] + r0[1] + r0[2] + r0[3];
    float qq = r1[0] + r1[1] + r1[2] + r1[3];
    float m = ss / (float)(B * C);
    mu_e[e] = m;
    rs_e[e] = rsqrtf(qq / (float)(B * C) - m * m + BN_EPS);
  }
}

__global__ void ed_update(float* __restrict__ ed, const float* __restrict__ agg,
                          const float* __restrict__ mu_e, const float* __restrict__ rs_e)
{
  long long idx = (long long)blockIdx.x * 256 + threadIdx.x;
  if (idx >= (long long)B * E * C) return;
  int e = (int)((idx / C) % E);
  float v = (agg[idx] - mu_e[e]) * rs_e[e];
  ed[idx] += fmaxf(v, 0.f);
}

// ------- sigmoid -> softmax over j -> msg, pre = U + msg; block per (b,i) -------
__global__ __launch_bounds__(256)
void msg_k(const float* __restrict__ ed, const float* __restrict__ ABUV,
           float* __restrict__ pre)
{
  const int bid = blockIdx.x;
  const int b = bid / N, i = bid % N;
  const int tid = threadIdx.x;
  for (int c = tid; c < C; c += 256) {
    float sv[N];
    float m = -1e30f;
#pragma unroll
    for (int jn = 0; jn < N; ++jn) {
      float xx = ed[((long long)b * E + i * N + jn) * C + c];
      float sg = 1.f / (1.f + __expf(-xx));
      sv[jn] = sg;
      m = fmaxf(m, sg);
    }
    float sum = 0.f;
#pragma unroll
    for (int jn = 0; jn < N; ++jn) { float ev = __expf(sv[jn] - m); sv[jn] = ev; sum += ev; }
    float acc = 0.f;
#pragma unroll
    for (int jn = 0; jn < N; ++jn)
      acc = fmaf(sv[jn], ABUV[(long long)(b * N + jn) * 2048 + 1536 + c], acc);
    acc /= (sum * (float)N);
    pre[(b * N + i) * C + c] = ABUV[(long long)(b * N + i) * 2048 + 1024 + c] + acc;
  }
}

__global__ __launch_bounds__(256)
void node_stats(const float* __restrict__ pre, float* __restrict__ mu_i,
                float* __restrict__ rs_i)
{
  const int i = blockIdx.x;
  const int tid = threadIdx.x;
  float s = 0.f, q = 0.f;
  for (int idx = tid; idx < B * C; idx += 256) {
    int b = idx >> 9, c = idx & 511;
    float v = pre[(b * N + i) * C + c];
    s += v; q += v * v;
  }
  for (int off = 32; off; off >>= 1) { s += __shfl_down(s, off); q += __shfl_down(q, off); }
  __shared__ float r0[4], r1[4];
  int wid = tid >> 6, lane = tid & 63;
  if (lane == 0) { r0[wid] = s; r1[wid] = q; }
  __syncthreads();
  if (tid == 0) {
    float ss = r0[0] + r0[1] + r0[2] + r0[3];
    float qq = r1[0] + r1[1] + r1[2] + r1[3];
    float m = ss / (float)(B * C);
    mu_i[i] = m;
    rs_i[i] = rsqrtf(qq / (float)(B * C) - m * m + BN_EPS);
  }
}

__global__ void xv_update(float* __restrict__ xv, const float* __restrict__ pre,
                          const float* __restrict__ mu_i, const float* __restrict__ rs_i)
{
  long long idx = (long long)blockIdx.x * 256 + threadIdx.x;
  if (idx >= (long long)B * N * C) return;
  int i = (int)((idx / C) % N);
  float v = xv[idx] + (pre[idx] - mu_i[i]) * rs_i[i];
  xv[idx] = fmaxf(v, 0.f);
}

// ---------------- cosine classifier ----------------
__global__ __launch_bounds__(256)
void cl_k(const float* __restrict__ xv, const float* __restrict__ sc,
          float* __restrict__ out)
{
  const int bid = blockIdx.x;
  const int b = bid / N, i = bid % N;
  const int tid = threadIdx.x;
  float sxx = 0.f, sss = 0.f, sxs = 0.f;
  for (int c = tid; c < C; c += 256) {
    float xvv = xv[(long long)(b * N + i) * C + c];
    float scv = fmaxf(sc[i * C + c], 0.f);
    sxx += xvv * xvv; sss += scv * scv; sxs += xvv * scv;
  }
  for (int off = 32; off; off >>= 1) {
    sxx += __shfl_down(sxx, off);
    sss += __shfl_down(sss, off);
    sxs += __shfl_down(sxs, off);
  }
  __shared__ float r0[4], r1[4], r2[4];
  int wid = tid >> 6, lane = tid & 63;
  if (lane == 0) { r0[wid] = sxx; r1[wid] = sss; r2[wid] = sxs; }
  __syncthreads();
  if (tid == 0) {
    float a = r0[0] + r0[1] + r0[2] + r0[3];
    float s = r1[0] + r1[1] + r1[2] + r1[3];
    float p = r2[0] + r2[1] + r2[2] + r2[3];
    float nx = fmaxf(sqrtf(a), 1e-12f);
    float ns = fmaxf(sqrtf(s), 1e-12f);
    out[b * N + i] = p / (nx * ns);
  }
}

// ---------------- cl_edge = ed @ efc_w + efc_b ----------------
__global__ __launch_bounds__(64)
void cledge_k(const float* __restrict__ ed, const float* __restrict__ w,
              const float* __restrict__ bias, float* __restrict__ out)
{
  const int bid = blockIdx.x;  // b*E + e
  const int lane = threadIdx.x;
  float a0 = 0, a1 = 0, a2 = 0, a3 = 0;
  for (int c = lane; c < C; c += 64) {
    float v = ed[(long long)bid * C + c];
    a0 = fmaf(v, w[c * 4 + 0], a0);
    a1 = fmaf(v, w[c * 4 + 1], a1);
    a2 = fmaf(v, w[c * 4 + 2], a2);
    a3 = fmaf(v, w[c * 4 + 3], a3);
  }
  for (int off = 32; off; off >>= 1) {
    a0 += __shfl_down(a0, off);
    a1 += __shfl_down(a1, off);
    a2 += __shfl_down(a2, off);
    a3 += __shfl_down(a3, off);
  }
  if (lane == 0) {
    out[B * N + bid * 4 + 0] = a0 + bias[0];
    out[B * N + bid * 4 + 1] = a1 + bias[1];
    out[B * N + bid * 4 + 2] = a2 + bias[2];
    out[B * N + bid * 4 + 3] = a3 + bias[3];
  }
}

} // namespace

extern "C" void kernel_launch(void* const* d_in, const int* in_sizes, int n_in,
                              void* d_out, int out_size, void* d_ws, size_t ws_size,
                              hipStream_t stream)
{
  (void)in_sizes; (void)n_in; (void)out_size; (void)ws_size;
  const float* x      = (const float*)d_in[0];
  const float* Wc     = (const float*)d_in[1];
  const float* bc     = (const float*)d_in[2];
  const float* fam_wq = (const float*)d_in[3];
  const float* fam_bq = (const float*)d_in[4];
  const float* fam_wk = (const float*)d_in[5];
  const float* fam_bk = (const float*)d_in[6];
  const float* fam_wv = (const float*)d_in[7];
  const float* fam_bv = (const float*)d_in[8];
  const float* arm_wq = (const float*)d_in[9];
  const float* arm_bq = (const float*)d_in[10];
  const float* arm_wk = (const float*)d_in[11];
  const float* arm_bk = (const float*)d_in[12];
  const float* arm_wv = (const float*)d_in[13];
  const float* arm_bv = (const float*)d_in[14];
  const float* ep_w   = (const float*)d_in[15];
  const float* ep_b   = (const float*)d_in[16];
  const float* gw[10] = {
    (const float*)d_in[17], (const float*)d_in[18], (const float*)d_in[19],
    (const float*)d_in[20], (const float*)d_in[21],
    (const float*)d_in[22], (const float*)d_in[23], (const float*)d_in[24],
    (const float*)d_in[25], (const float*)d_in[26]};
  const float* sc     = (const float*)d_in[27];
  const float* efc_w  = (const float*)d_in[28];
  const float* efc_b  = (const float*)d_in[29];
  float* out = (float*)d_out;

  char* wsb = (char*)d_ws;
  size_t off = 0;
  auto allocf = [&](size_t n) { float* p = (float*)(wsb + off); off += ((n * 4 + 255) / 256) * 256; return p; };
  auto allocu = [&](size_t n) { unsigned short* p = (unsigned short*)(wsb + off); off += ((n * 2 + 255) / 256) * 256; return p; };

  // region1: h_t early; later S1 | Sc; after Sc dead: fe/EW/agg
  float* region1 = allocf(3356160);
  float* h_t = region1;
  float* S1  = region1;                    // 589824
  float* Sc  = region1 + 589824;           // 2766336 (8*588*588)
  float* fe  = region1 + 589824;
  float* EW  = region1 + 1179648;
  float* agg = region1 + 1769472;
  // region2: f_u early; reused for qf (fp32) + kfb (bf16) after q1 GEMM
  float* region2 = allocf(2408448);
  float* f_u = region2;
  float* qf  = region2;
  unsigned short* kfb = (unsigned short*)(region2 + 1204224);  // (4704+64)x256 bf16 fits

  float* mu_h = allocf(6144);
  float* rs_h = allocf(6144);
  float* bnp_s = allocf(49152);
  float* bnp_q = allocf(49152);
  float* f_v  = allocf(49152);
  float* q1   = allocf(1204224);
  float* kx_slot = allocf(100352);
  unsigned short* kxb = (unsigned short*)kx_slot;              // (392+64)x256 bf16 fits
  float* vx   = allocf(200704);
  float* feat = allocf(2408448);
  float* vfe  = allocf(2408448);
  float* W2   = allocf(262144);
  float* b2   = allocf(512);
  float* Sf   = allocf(230496);            // 8*588*49
  float* Gm   = allocf(230496);            // 96*49*49
  float* eS   = allocf(2304);
  float* me   = allocf(144);
  float* rve  = allocf(144);
  float* mask = allocf(1152);
  float* ABUV = allocf(196608);
  float* pre  = allocf(49152);
  float* mu_e = allocf(144);
  float* rs_e = allocf(144);
  float* mu_i = allocf(16);
  float* rs_i = allocf(16);

  unsigned short* Wct    = allocu(3145728);
  unsigned short* famqt  = allocu(131072);
  unsigned short* famkt  = allocu(131072);
  unsigned short* famvt  = allocu(262144);
  unsigned short* armqt  = allocu(131072);
  unsigned short* armkt  = allocu(131072);
  unsigned short* epwt   = allocu(262144);
  unsigned short* W2t    = allocu(262144);
  unsigned short* vfeb   = allocu(2441216);  // (4704+64)x512
  unsigned short* ABUVt0 = allocu(1048576);
  unsigned short* ABUVt1 = allocu(1048576);
  unsigned short* wet0   = allocu(262144);
  unsigned short* wet1   = allocu(262144);

  dim3 blk(256);

  // -------- weight transpose+cast (28 jobs) --------
  TCJobs tj{};
  int jn = 0;
  for (int n = 0; n < 12; ++n) { tj.src[jn] = Wc + (size_t)n * C * C; tj.dst[jn] = Wct + (size_t)n * C * C; tj.nn[jn] = C; ++jn; }
  tj.src[jn] = fam_wq; tj.dst[jn] = famqt; tj.nn[jn] = H; ++jn;
  tj.src[jn] = fam_wk; tj.dst[jn] = famkt; tj.nn[jn] = H; ++jn;
  tj.src[jn] = fam_wv; tj.dst[jn] = famvt; tj.nn[jn] = C; ++jn;
  tj.src[jn] = arm_wq; tj.dst[jn] = armqt; tj.nn[jn] = H; ++jn;
  tj.src[jn] = arm_wk; tj.dst[jn] = armkt; tj.nn[jn] = H; ++jn;
  tj.src[jn] = ep_w;   tj.dst[jn] = epwt;  tj.nn[jn] = C; ++jn;
  tj.src[jn] = gw[2];  tj.dst[jn] = wet0;  tj.nn[jn] = C; ++jn;
  tj.src[jn] = gw[7];  tj.dst[jn] = wet1;  tj.nn[jn] = C; ++jn;
  tj.src[jn] = gw[0];  tj.dst[jn] = ABUVt0;                 tj.nn[jn] = C; ++jn;
  tj.src[jn] = gw[1];  tj.dst[jn] = ABUVt0 + 1 * C * C;     tj.nn[jn] = C; ++jn;
  tj.src[jn] = gw[3];  tj.dst[jn] = ABUVt0 + 2 * C * C;     tj.nn[jn] = C; ++jn;
  tj.src[jn] = gw[4];  tj.dst[jn] = ABUVt0 + 3 * C * C;     tj.nn[jn] = C; ++jn;
  tj.src[jn] = gw[5];  tj.dst[jn] = ABUVt1;                 tj.nn[jn] = C; ++jn;
  tj.src[jn] = gw[6];  tj.dst[jn] = ABUVt1 + 1 * C * C;     tj.nn[jn] = C; ++jn;
  tj.src[jn] = gw[8];  tj.dst[jn] = ABUVt1 + 2 * C * C;     tj.nn[jn] = C; ++jn;
  tj.src[jn] = gw[9];  tj.dst[jn] = ABUVt1 + 3 * C * C;     tj.nn[jn] = C; ++jn;
  tcast_k<<<dim3(16, 16, 28), blk, 0, stream>>>(tj);

  b2full_k<<<dim3(2), blk, 0, stream>>>(arm_bv, ep_w, ep_b, b2);

  // h[n] = x @ Wc[n] + bc[n]
  gemm_mfma<<<dim3(7, 8, 12), blk, 0, stream>>>(x, Wct, bc, h_t, nullptr, M_BD, C, C,
      0LL, (long long)C * C, (long long)C, (long long)M_BD * C);
  bn_stats_part<<<dim3(24, 8), blk, 0, stream>>>(h_t, bnp_s, bnp_q);
  bn_stats_final<<<dim3(24), blk, 0, stream>>>(bnp_s, bnp_q, mu_h, rs_h);
  fu_fv<<<dim3(B * N, 2), blk, 0, stream>>>(h_t, mu_h, rs_h, f_u, f_v);

  // fam projections
  gemm_mfma<<<dim3(74, 4, 1), blk, 0, stream>>>(f_u, famqt, fam_bq, q1, nullptr, M_BND, H, C, 0, 0, 0, 0);
  gemm_mfma<<<dim3(7, 4, 1),  blk, 0, stream>>>(x, famkt, fam_bk, nullptr, kxb, M_BD, H, C, 0, 0, 0, 0);
  gemm_mfma<<<dim3(7, 8, 1),  blk, 0, stream>>>(x, famvt, fam_bv, vx, nullptr, M_BD, C, C, 0, 0, 0, 0);
  // Sf[b] = q1[b] @ kx[b]^T  (588 x 49)
  gemm_mfma<<<dim3(10, 1, 8), blk, 0, stream>>>(q1, kxb, nullptr, Sf, nullptr, 588, 49, H,
      588LL * 256, 49LL * 256, 0LL, 588LL * 49);
  fam_finish<<<dim3(B * N), blk, 0, stream>>>(Sf, vx, feat);

  // arm projections; ep_w folded through v (softmax rows sum to 1)
  gemm_mfma<<<dim3(74, 4, 1), blk, 0, stream>>>(feat, armqt, arm_bq, qf, nullptr, M_BND, H, C, 0, 0, 0, 0);
  gemm_mfma<<<dim3(74, 4, 1), blk, 0, stream>>>(feat, armkt, arm_bk, nullptr, kfb, M_BND, H, C, 0, 0, 0, 0);
  gemm_mfma<<<dim3(8, 8, 1),  blk, 0, stream>>>(arm_wv, epwt, nullptr, W2, nullptr, C, C, C, 0, 0, 0, 0);
  {
    TCJobs tj2{};
    tj2.src[0] = W2; tj2.dst[0] = W2t; tj2.nn[0] = C;
    tcast_k<<<dim3(16, 16, 1), blk, 0, stream>>>(tj2);
  }
  gemm_mfma<<<dim3(74, 8, 1), blk, 0, stream>>>(feat, W2t, b2, vfe, vfeb, M_BND, C, C, 0, 0, 0, 0);

  // Sc[b] = qf[b] @ kf[b]^T  (588 x 588)
  gemm_mfma<<<dim3(10, 10, 8), blk, 0, stream>>>(qf, kfb, nullptr, Sc, nullptr, 588, 588, H,
      588LL * 256, 588LL * 256, 0LL, 588LL * 588);
  // G[node] = vfe_node @ vfe_node^T  (49 x 49)
  gemm_mfma<<<dim3(1, 1, 96), blk, 0, stream>>>(vfe, vfeb, nullptr, Gm, nullptr, D, D, C,
      49LL * 512, 49LL * 512, 0LL, 49LL * 49);

  // per-edge: softmax + colsum@V (S1) + a(AG)a (st2)
  edge_finish<<<dim3(B * E), blk, 0, stream>>>(Sc, Gm, vfe, S1, eS);
  edge_me<<<dim3(1), blk, 0, stream>>>(eS, me, rve);
  mask_k<<<dim3(B), blk, 0, stream>>>(f_v, mask);
  fe_k<<<dim3((B * E * C + 255) / 256), blk, 0, stream>>>(S1, me, rve, mask, fe);

  // two GNN layers
  for (int L = 0; L < 2; ++L) {
    const unsigned short* ABUVt = L ? ABUVt1 : ABUVt0;
    const unsigned short* wet   = L ? wet1 : wet0;
    gemm_mfma<<<dim3(2, 32, 1), blk, 0, stream>>>(f_v, ABUVt, nullptr, ABUV, nullptr, B * N, 2048, C, 0, 0, 0, 0);
    gemm_mfma<<<dim3(18, 8, 1), blk, 0, stream>>>(fe, wet, nullptr, EW, nullptr, B * E, C, C, 0, 0, 0, 0);
    agg_stats<<<dim3(E), blk, 0, stream>>>(ABUV, EW, agg, mu_e, rs_e);
    ed_update<<<dim3((B * E * C + 255) / 256), blk, 0, stream>>>(fe, agg, mu_e, rs_e);
    msg_k<<<dim3(B * N), blk, 0, stream>>>(fe, ABUV, pre);
    node_stats<<<dim3(N), blk, 0, stream>>>(pre, mu_i, rs_i);
    xv_update<<<dim3((B * N * C + 255) / 256), blk, 0, stream>>>(f_v, pre, mu_i, rs_i);
  }

  cl_k<<<dim3(B * N), blk, 0, stream>>>(f_v, sc, out);
  cledge_k<<<dim3(B * E), dim3(64), 0, stream>>>(fe, efc_w, efc_b, out);
}

// Round 4
// 292.321 us; speedup vs baseline: 7.6461x; 1.2445x over previous
//
#include <hip/hip_runtime.h>
#include <math.h>

namespace {

constexpr int B = 8, D = 49, C = 512, N = 12, H = 256, E = 144;
constexpr int M_BD  = B * D;        // 392
constexpr int M_BND = B * N * D;    // 4704
constexpr float BN_EPS = 1e-5f;
constexpr float ATT_SCALE = 0.0625f; // (C/2)^-0.5

typedef __attribute__((ext_vector_type(4))) float  floatx4;
typedef __attribute__((ext_vector_type(8))) short  shortx8;

__device__ inline unsigned short f2bf(float f) {
  unsigned u = __float_as_uint(f);
  return (unsigned short)((u + 0x7fffu + ((u >> 16) & 1u)) >> 16);
}
__device__ inline float bf2f(unsigned short u) {
  return __uint_as_float(((unsigned)u) << 16);
}

// ---------------- transpose+cast fp32 [K=512][Nn] -> bf16 [Nn][512] ----------------
struct TCJobs {
  const float* src[28];
  unsigned short* dst[28];
  int nn[28];
};

__global__ __launch_bounds__(256)
void tcast_k(TCJobs jobs)
{
  const int z = blockIdx.z;
  const float* src = jobs.src[z];
  unsigned short* dst = jobs.dst[z];
  const int Nn = jobs.nn[z];
  const int tx = blockIdx.x, ty = blockIdx.y;
  if (tx * 32 >= Nn) return;
  __shared__ float t[32][33];
  const int tid = threadIdx.x;
  const int lr = tid >> 5, lc = tid & 31;
#pragma unroll
  for (int p = 0; p < 4; ++p) {
    int k = ty * 32 + p * 8 + lr;
    t[p * 8 + lr][lc] = src[(long long)k * Nn + tx * 32 + lc];
  }
  __syncthreads();
#pragma unroll
  for (int p = 0; p < 4; ++p) {
    int n = tx * 32 + p * 8 + lr;
    dst[(long long)n * 512 + ty * 32 + lc] = f2bf(t[lc][p * 8 + lr]);
  }
}

// -------- x cast to bf16 (row-major) + bias concats --------
__global__ __launch_bounds__(256)
void castrow_k(const float* __restrict__ x, unsigned short* __restrict__ xb,
               const float* __restrict__ bk, const float* __restrict__ bv,
               const float* __restrict__ bq2, const float* __restrict__ bk2,
               float* __restrict__ kvbias, float* __restrict__ qkbias)
{
  int idx = blockIdx.x * 256 + threadIdx.x;
  int i8 = idx * 8;
  if (i8 < M_BD * C) {
    float4 a = *reinterpret_cast<const float4*>(x + i8);
    float4 b = *reinterpret_cast<const float4*>(x + i8 + 4);
    shortx8 o;
    o[0]=(short)f2bf(a.x); o[1]=(short)f2bf(a.y); o[2]=(short)f2bf(a.z); o[3]=(short)f2bf(a.w);
    o[4]=(short)f2bf(b.x); o[5]=(short)f2bf(b.y); o[6]=(short)f2bf(b.z); o[7]=(short)f2bf(b.w);
    *reinterpret_cast<shortx8*>(xb + i8) = o;
  }
  if (idx < 256) { kvbias[idx] = bk[idx]; qkbias[idx] = bq2[idx]; qkbias[256 + idx] = bk2[idx]; }
  if (idx < 512) kvbias[256 + idx] = bv[idx];
}

// ---------------- bf16 MFMA GEMM: A fp32/bf16 [M][lda], Bt bf16 [Nn][ldb] ----------
// C = A @ Bt^T (+bias). Optional fp32 out Co and/or bf16 out Cb, both ldc.
// K multiple of 64. Bt rows up to round64(Nn)-1 are READ (pad allocations!).
__global__ __launch_bounds__(256)
void gemm_mfma(const void* __restrict__ Ain, const unsigned short* __restrict__ Bt,
               const float* __restrict__ bias, float* __restrict__ Co,
               unsigned short* __restrict__ Cb,
               int M, int Nn, int K, int lda, int ldb, int ldc, int abf,
               long long sA, long long sB, long long sBias, long long sC)
{
  const int z = blockIdx.z;
  const float* Af = abf ? nullptr : ((const float*)Ain + z * sA);
  const unsigned short* Ab = abf ? ((const unsigned short*)Ain + z * sA) : nullptr;
  Bt += z * sB;
  float* co = Co ? Co + z * sC : nullptr;
  unsigned short* cb = Cb ? Cb + z * sC : nullptr;
  const float* bp = bias ? bias + z * sBias : nullptr;

  __shared__ short As[64 * 72];
  __shared__ short Bs[64 * 72];

  const int tid = threadIdx.x;
  const int row0 = blockIdx.x * 64, col0 = blockIdx.y * 64;
  const int wid = tid >> 6, lane = tid & 63;
  const int wr = wid >> 1, wc = wid & 1;
  const int lr = lane & 15, lg = lane >> 4;

  floatx4 acc00 = {0.f,0.f,0.f,0.f}, acc01 = {0.f,0.f,0.f,0.f};
  floatx4 acc10 = {0.f,0.f,0.f,0.f}, acc11 = {0.f,0.f,0.f,0.f};

  const int r = tid >> 2, seg = tid & 3;
  const int gr = row0 + r, gn = col0 + r;
  short* aw = &As[r * 72 + seg * 16];
  short* bw = &Bs[r * 72 + seg * 16];
  const shortx8 zz = {0,0,0,0,0,0,0,0};

  for (int k0 = 0; k0 < K; k0 += 64) {
    shortx8 w0, w1;
    if (gr < M) {
      if (abf) {
        const shortx8* ap = reinterpret_cast<const shortx8*>(Ab + (long long)gr * lda + seg * 16 + k0);
        w0 = ap[0]; w1 = ap[1];
      } else {
        const float4* ap = reinterpret_cast<const float4*>(Af + (long long)gr * lda + seg * 16 + k0);
        float4 fa0 = ap[0], fa1 = ap[1], fa2 = ap[2], fa3 = ap[3];
        w0[0]=(short)f2bf(fa0.x); w0[1]=(short)f2bf(fa0.y); w0[2]=(short)f2bf(fa0.z); w0[3]=(short)f2bf(fa0.w);
        w0[4]=(short)f2bf(fa1.x); w0[5]=(short)f2bf(fa1.y); w0[6]=(short)f2bf(fa1.z); w0[7]=(short)f2bf(fa1.w);
        w1[0]=(short)f2bf(fa2.x); w1[1]=(short)f2bf(fa2.y); w1[2]=(short)f2bf(fa2.z); w1[3]=(short)f2bf(fa2.w);
        w1[4]=(short)f2bf(fa3.x); w1[5]=(short)f2bf(fa3.y); w1[6]=(short)f2bf(fa3.z); w1[7]=(short)f2bf(fa3.w);
      }
    } else { w0 = zz; w1 = zz; }
    const shortx8* bp8 = reinterpret_cast<const shortx8*>(Bt + (long long)gn * ldb + seg * 16 + k0);
    shortx8 b0v = bp8[0];
    shortx8 b1v = bp8[1];

    __syncthreads();
    *reinterpret_cast<shortx8*>(aw)     = w0;
    *reinterpret_cast<shortx8*>(aw + 8) = w1;
    *reinterpret_cast<shortx8*>(bw)     = b0v;
    *reinterpret_cast<shortx8*>(bw + 8) = b1v;
    __syncthreads();

#pragma unroll
    for (int kt = 0; kt < 2; ++kt) {
      shortx8 a0 = *reinterpret_cast<const shortx8*>(&As[(wr*32      + lr) * 72 + kt*32 + lg*8]);
      shortx8 a1 = *reinterpret_cast<const shortx8*>(&As[(wr*32 + 16 + lr) * 72 + kt*32 + lg*8]);
      shortx8 bb0 = *reinterpret_cast<const shortx8*>(&Bs[(wc*32      + lr) * 72 + kt*32 + lg*8]);
      shortx8 bb1 = *reinterpret_cast<const shortx8*>(&Bs[(wc*32 + 16 + lr) * 72 + kt*32 + lg*8]);
      acc00 = __builtin_amdgcn_mfma_f32_16x16x32_bf16(a0, bb0, acc00, 0, 0, 0);
      acc01 = __builtin_amdgcn_mfma_f32_16x16x32_bf16(a0, bb1, acc01, 0, 0, 0);
      acc10 = __builtin_amdgcn_mfma_f32_16x16x32_bf16(a1, bb0, acc10, 0, 0, 0);
      acc11 = __builtin_amdgcn_mfma_f32_16x16x32_bf16(a1, bb1, acc11, 0, 0, 0);
    }
  }

  const int colA = col0 + wc * 32 + lr;
  const int colB = colA + 16;
  const bool okA = colA < Nn, okB = colB < Nn;
  const float biasA = (bp && okA) ? bp[colA] : 0.f;
  const float biasB = (bp && okB) ? bp[colB] : 0.f;
  const int rb0 = row0 + wr * 32 + lg * 4;
  const int rb1 = rb0 + 16;
#pragma unroll
  for (int jj = 0; jj < 4; ++jj) {
    int ra = rb0 + jj, rb = rb1 + jj;
    float v00 = acc00[jj] + biasA, v01 = acc01[jj] + biasB;
    float v10 = acc10[jj] + biasA, v11 = acc11[jj] + biasB;
    if (ra < M) {
      if (co) { if (okA) co[(long long)ra * ldc + colA] = v00;
                if (okB) co[(long long)ra * ldc + colB] = v01; }
      if (cb) { if (okA) cb[(long long)ra * ldc + colA] = f2bf(v00);
                if (okB) cb[(long long)ra * ldc + colB] = f2bf(v01); }
    }
    if (rb < M) {
      if (co) { if (okA) co[(long long)rb * ldc + colA] = v10;
                if (okB) co[(long long)rb * ldc + colB] = v11; }
      if (cb) { if (okA) cb[(long long)rb * ldc + colA] = f2bf(v10);
                if (okB) cb[(long long)rb * ldc + colB] = f2bf(v11); }
    }
  }
}

// ---------------- BN stats per (n,c): 8 row-slices then reduce ----------------
__global__ __launch_bounds__(256)
void bn_stats_part(const float* __restrict__ h, float* __restrict__ ps,
                   float* __restrict__ pq)
{
  int idx = blockIdx.x * 256 + threadIdx.x;
  int n = idx >> 9, c = idx & 511;
  int slice = blockIdx.y;
  const float* p = h + (long long)n * M_BD * C + (long long)slice * 49 * C + c;
  float s = 0.f, q = 0.f;
  for (int rr = 0; rr < 49; ++rr) { float v = p[(long long)rr * C]; s += v; q += v * v; }
  ps[slice * (N * C) + idx] = s;
  pq[slice * (N * C) + idx] = q;
}

__global__ __launch_bounds__(256)
void bn_stats_final(const float* __restrict__ ps, const float* __restrict__ pq,
                    float* __restrict__ mu, float* __restrict__ rs)
{
  int idx = blockIdx.x * 256 + threadIdx.x;
  float s = 0.f, q = 0.f;
#pragma unroll
  for (int sl = 0; sl < 8; ++sl) { s += ps[sl * (N * C) + idx]; q += pq[sl * (N * C) + idx]; }
  float m = s / (float)M_BD;
  mu[idx] = m;
  rs[idx] = rsqrtf(q / (float)M_BD - m * m + BN_EPS);
}

// ------- f_u = relu(norm(h)) -> bf16, f_v = mean_d f_u -> fp32 ; grid (B*N, 2) -------
__global__ __launch_bounds__(256)
void fu_fv(const float* __restrict__ h, const float* __restrict__ mu,
           const float* __restrict__ rs, unsigned short* __restrict__ fub,
           float* __restrict__ fv)
{
  const int bid = blockIdx.x;
  const int b = bid / N, n = bid % N;
  const int c = blockIdx.y * 256 + threadIdx.x;
  float m = mu[n * C + c], rv = rs[n * C + c];
  float acc = 0.f;
  for (int d = 0; d < D; ++d) {
    float v = h[((long long)n * M_BD + b * D + d) * C + c];
    v = fmaxf((v - m) * rv, 0.f);
    fub[((long long)bid * D + d) * C + c] = f2bf(v);
    acc += v;
  }
  fv[(long long)bid * C + c] = acc * (1.0f / (float)D);
}

// ---------------- row softmax of Sf (4704 rows x 49) -> bf16 padded K=64 ----------------
__global__ __launch_bounds__(256)
void fam_softmax(const float* __restrict__ Sf, unsigned short* __restrict__ Ppb)
{
  int row = blockIdx.x * 256 + threadIdx.x;
  if (row >= M_BND) return;
  const float* p = Sf + (long long)row * 49;
  float v[49];
  float m = -1e30f;
#pragma unroll
  for (int j = 0; j < 49; ++j) { v[j] = p[j] * ATT_SCALE; m = fmaxf(m, v[j]); }
  float s = 0.f;
#pragma unroll
  for (int j = 0; j < 49; ++j) { v[j] = __expf(v[j] - m); s += v[j]; }
  float inv = 1.f / s;
  unsigned short* o = Ppb + (long long)row * 64;
#pragma unroll
  for (int j = 0; j < 49; ++j) o[j] = f2bf(v[j] * inv);
#pragma unroll
  for (int j = 49; j < 64; ++j) o[j] = 0;
}

// ------- transpose vx slice of kxvx_b: per b, [49][512] -> [512][64] bf16 zero-pad -------
__global__ __launch_bounds__(256)
void vxt_k(const unsigned short* __restrict__ kvx, unsigned short* __restrict__ vxtb)
{
  const int b = blockIdx.x, cc = blockIdx.y;
  __shared__ unsigned short t[49][65];
  const int tid = threadIdx.x;
  for (int idx = tid; idx < 49 * 64; idx += 256) {
    int rr = idx >> 6, k = idx & 63;
    t[rr][k] = kvx[(long long)(b * 49 + rr) * 768 + 256 + cc * 64 + k];
  }
  __syncthreads();
  for (int idx = tid; idx < 64 * 64; idx += 256) {
    int n = idx >> 6, kk = idx & 63;
    vxtb[((long long)b * 512 + cc * 64 + n) * 64 + kk] = (kk < 49) ? t[kk][n] : (unsigned short)0;
  }
}

// ------- edge finish: softmax + colsum@V (S1) + st2 = <A^T A, G> via MFMA -------
__global__ __launch_bounds__(256)
void edge_finish(const float* __restrict__ Sc, const float* __restrict__ G,
                 const unsigned short* __restrict__ vfeb,
                 float* __restrict__ S1, float* __restrict__ eS)
{
  const int bid = blockIdx.x;           // b*E + e
  const int b = bid / E, e = bid % E;
  const int i = e / N, j = e % N;
  const float* Scb = Sc + (long long)b * 588 * 588 + (long long)(j * 49) * 588 + i * 49;
  const float* Gp  = G + (long long)(b * N + i) * 2401;
  const unsigned short* Vp = vfeb + (long long)(b * N + i) * D * 512;

  __shared__ float aT[49][53];          // aT[dj][di] = probs[di][dj]
  __shared__ float g[49][53];
  __shared__ unsigned short abT[64][72];
  __shared__ float ws[52];
  __shared__ float r0[4], r1[4];
  const int tid = threadIdx.x;
  const int wid = tid >> 6, lane = tid & 63;
  const int lr = lane & 15, lg = lane >> 4;

  for (int idx = tid; idx < 49 * 49; idx += 256) {
    int di = idx / 49, dj = idx - di * 49;
    aT[dj][di] = Scb[di * 588 + dj] * ATT_SCALE;
    g[di][dj] = Gp[idx];
  }
  __syncthreads();
  if (tid < D) {
    float m = -1e30f;
    for (int jj = 0; jj < D; ++jj) m = fmaxf(m, aT[jj][tid]);
    float s = 0.f;
    for (int jj = 0; jj < D; ++jj) { float ev = __expf(aT[jj][tid] - m); aT[jj][tid] = ev; s += ev; }
    float inv = 1.f / s;
    for (int jj = 0; jj < D; ++jj) aT[jj][tid] *= inv;
  }
  __syncthreads();
  for (int idx = tid; idx < 64 * 64; idx += 256) {
    int dj = idx >> 6, di = idx & 63;
    float v = (dj < D && di < D) ? aT[dj][di] : 0.f;
    abT[dj][di] = f2bf(v);
  }
  if (tid < D) {
    float s = 0.f;
    for (int di = 0; di < D; ++di) s += aT[tid][di];
    ws[tid] = s;
  }
  __syncthreads();

  // M = A^T A, st2 = sum M .* G   (wave w handles output rows w*16..w*16+15)
  floatx4 acc[4];
#pragma unroll
  for (int tk = 0; tk < 4; ++tk) acc[tk] = floatx4{0.f,0.f,0.f,0.f};
  shortx8 af0 = *reinterpret_cast<const shortx8*>(&abT[wid * 16 + lr][lg * 8]);
  shortx8 af1 = *reinterpret_cast<const shortx8*>(&abT[wid * 16 + lr][32 + lg * 8]);
#pragma unroll
  for (int tk = 0; tk < 4; ++tk) {
    shortx8 bf0v = *reinterpret_cast<const shortx8*>(&abT[tk * 16 + lr][lg * 8]);
    shortx8 bf1v = *reinterpret_cast<const shortx8*>(&abT[tk * 16 + lr][32 + lg * 8]);
    acc[tk] = __builtin_amdgcn_mfma_f32_16x16x32_bf16(af0, bf0v, acc[tk], 0, 0, 0);
    acc[tk] = __builtin_amdgcn_mfma_f32_16x16x32_bf16(af1, bf1v, acc[tk], 0, 0, 0);
  }
  float st2 = 0.f;
#pragma unroll
  for (int tk = 0; tk < 4; ++tk) {
    int kcol = tk * 16 + lr;
#pragma unroll
    for (int rg = 0; rg < 4; ++rg) {
      int jrow = wid * 16 + lg * 4 + rg;
      if (jrow < D && kcol < D) st2 = fmaf(acc[tk][rg], g[jrow][kcol], st2);
    }
  }

  // S1 = colsum(A) @ V
  float st = 0.f;
#pragma unroll
  for (int cc = 0; cc < C; cc += 256) {
    int cg = cc + tid;
    float s1 = 0.f;
    for (int dk = 0; dk < D; ++dk) s1 = fmaf(ws[dk], bf2f(Vp[dk * 512 + cg]), s1);
    S1[(long long)bid * C + cg] = s1;
    st += s1;
  }
  for (int off = 32; off; off >>= 1) { st += __shfl_down(st, off); st2 += __shfl_down(st2, off); }
  if (lane == 0) { r0[wid] = st; r1[wid] = st2; }
  __syncthreads();
  if (tid == 0) {
    eS[bid * 2 + 0] = r0[0] + r0[1] + r0[2] + r0[3];
    eS[bid * 2 + 1] = r1[0] + r1[1] + r1[2] + r1[3];
  }
}

// ---------------- b2 = arm_bv @ ep_w + ep_b ----------------
__global__ void b2full_k(const float* __restrict__ bv, const float* __restrict__ epw,
                         const float* __restrict__ epb, float* __restrict__ b2)
{
  int c = blockIdx.x * blockDim.x + threadIdx.x;
  if (c >= C) return;
  float s = epb[c];
  for (int k = 0; k < C; ++k) s = fmaf(bv[k], epw[k * C + c], s);
  b2[c] = s;
}

// ---------------- per-e BN constants for f_e ----------------
__global__ void edge_me(const float* __restrict__ eS, float* __restrict__ me,
                        float* __restrict__ rve)
{
  int e = blockIdx.x * blockDim.x + threadIdx.x;
  if (e >= E) return;
  float s = 0.f, q = 0.f;
  for (int b = 0; b < B; ++b) { s += eS[(b * E + e) * 2]; q += eS[(b * E + e) * 2 + 1]; }
  const float inv = 1.f / (float)(B * D * C);
  float m = s * inv;
  me[e] = m;
  rve[e] = rsqrtf(q * inv - m * m + BN_EPS);
}

// ---------------- cosine-similarity mask, one block per b ----------------
__global__ __launch_bounds__(256)
void mask_k(const float* __restrict__ fv, float* __restrict__ mask)
{
  const int b = blockIdx.x;
  __shared__ float fl[N][C];
  __shared__ float adj[N][N];
  __shared__ float nrm[N];
  __shared__ float dis[N];
  const int tid = threadIdx.x;
  for (int idx = tid; idx < N * C; idx += 256)
    fl[idx / C][idx % C] = fv[(long long)b * N * C + idx];
  __syncthreads();
  if (tid < N * N) {
    int i = tid / N, j = tid % N;
    float s = 0.f;
    for (int k = 0; k < C; ++k) s += fl[i][k] * fl[j][k];
    adj[i][j] = s;
  }
  __syncthreads();
  if (tid < N) nrm[tid] = fmaxf(sqrtf(adj[tid][tid]), 1e-12f);
  __syncthreads();
  if (tid < N * N) {
    int i = tid / N, j = tid % N;
    adj[i][j] = adj[i][j] / (nrm[i] * nrm[j]);
  }
  __syncthreads();
  if (tid < N) {
    float s = 0.f;
    for (int j = 0; j < N; ++j) s += adj[tid][j];
    dis[tid] = rsqrtf(s);
  }
  __syncthreads();
  if (tid < N * N) {
    int i = tid / N, j = tid % N;
    mask[b * E + tid] = adj[i][j] * dis[i] * dis[j];
  }
}

// ---------------- f_e = (S1/D - me)*rve * mask ----------------
__global__ void fe_k(const float* __restrict__ S1, const float* __restrict__ me,
                     const float* __restrict__ rve, const float* __restrict__ mask,
                     float* __restrict__ fe)
{
  long long idx = (long long)blockIdx.x * 256 + threadIdx.x;
  if (idx >= (long long)B * E * C) return;
  long long be = idx / C;
  int e = (int)(be % E);
  fe[idx] = (S1[idx] * (1.0f / (float)D) - me[e]) * rve[e] * mask[be];
}

// ---------------- GNN: BN stats per e over agg = A[i]+B[j]+EW[e] (recomputed) ----------------
__global__ __launch_bounds__(256)
void agg_stats(const float* __restrict__ ABUV, const float* __restrict__ EW,
               float* __restrict__ mu_e, float* __restrict__ rs_e)
{
  const int e = blockIdx.x;
  const int i = e / N, j = e % N;
  const int tid = threadIdx.x;
  float s = 0.f, q = 0.f;
  for (int idx = tid; idx < B * C; idx += 256) {
    int b = idx >> 9, c = idx & 511;
    float v = ABUV[(long long)(b * N + i) * 2048 + c]
            + ABUV[(long long)(b * N + j) * 2048 + 512 + c]
            + EW[((long long)b * E + e) * C + c];
    s += v; q += v * v;
  }
  for (int off = 32; off; off >>= 1) { s += __shfl_down(s, off); q += __shfl_down(q, off); }
  __shared__ float r0[4], r1[4];
  int wid = tid >> 6, lane = tid & 63;
  if (lane == 0) { r0[wid] = s; r1[wid] = q; }
  __syncthreads();
  if (tid == 0) {
    float ss = r0[0] + r0[1] + r0[2] + r0[3];
    float qq = r1[0] + r1[1] + r1[2] + r1[3];
    float m = ss / (float)(B * C);
    mu_e[e] = m;
    rs_e[e] = rsqrtf(qq / (float)(B * C) - m * m + BN_EPS);
  }
}

// ------- fused: ed update (BN+relu+residual) + sigmoid/softmax msg + pre; block (b,i) -------
__global__ __launch_bounds__(256)
void edmsg_k(float* __restrict__ fe, const float* __restrict__ ABUV,
             const float* __restrict__ EW, const float* __restrict__ mu_e,
             const float* __restrict__ rs_e, float* __restrict__ pre)
{
  const int bid = blockIdx.x;
  const int b = bid / N, i = bid % N;
  const int tid = threadIdx.x;
  for (int c = tid; c < C; c += 256) {
    float ai = ABUV[(long long)(b * N + i) * 2048 + c];
    float sv[N];
    float m = -1e30f;
#pragma unroll
    for (int jn = 0; jn < N; ++jn) {
      int e = i * N + jn;
      float v = ai + ABUV[(long long)(b * N + jn) * 2048 + 512 + c]
              + EW[((long long)b * E + e) * C + c];
      v = (v - mu_e[e]) * rs_e[e];
      float ed = fe[((long long)b * E + e) * C + c] + fmaxf(v, 0.f);
      fe[((long long)b * E + e) * C + c] = ed;
      float sg = 1.f / (1.f + __expf(-ed));
      sv[jn] = sg; m = fmaxf(m, sg);
    }
    float sum = 0.f;
#pragma unroll
    for (int jn = 0; jn < N; ++jn) { float ev = __expf(sv[jn] - m); sv[jn] = ev; sum += ev; }
    float acc = 0.f;
#pragma unroll
    for (int jn = 0; jn < N; ++jn)
      acc = fmaf(sv[jn], ABUV[(long long)(b * N + jn) * 2048 + 1536 + c], acc);
    acc /= (sum * (float)N);
    pre[(long long)bid * C + c] = ABUV[(long long)bid * 2048 + 1024 + c] + acc;
  }
}

// ---------------- node BN partials: grid (N, B) ----------------
__global__ __launch_bounds__(256)
void node_part(const float* __restrict__ pre, float* __restrict__ nps,
               float* __restrict__ npq)
{
  const int i = blockIdx.x, b = blockIdx.y;
  const int tid = threadIdx.x;
  float v0 = pre[(long long)(b * N + i) * C + tid];
  float v1 = pre[(long long)(b * N + i) * C + 256 + tid];
  float s = v0 + v1, q = v0 * v0 + v1 * v1;
  for (int off = 32; off; off >>= 1) { s += __shfl_down(s, off); q += __shfl_down(q, off); }
  __shared__ float r0[4], r1[4];
  int wid = tid >> 6, lane = tid & 63;
  if (lane == 0) { r0[wid] = s; r1[wid] = q; }
  __syncthreads();
  if (tid == 0) {
    nps[i * B + b] = r0[0] + r0[1] + r0[2] + r0[3];
    npq[i * B + b] = r1[0] + r1[1] + r1[2] + r1[3];
  }
}

__global__ void xv_update(float* __restrict__ xv, const float* __restrict__ pre,
                          const float* __restrict__ nps, const float* __restrict__ npq)
{
  long long idx = (long long)blockIdx.x * 256 + threadIdx.x;
  if (idx >= (long long)B * N * C) return;
  int i = (int)((idx / C) % N);
  float s = 0.f, q = 0.f;
#pragma unroll
  for (int bb = 0; bb < B; ++bb) { s += nps[i * B + bb]; q += npq[i * B + bb]; }
  float mu = s * (1.f / (float)(B * C));
  float rs = rsqrtf(q * (1.f / (float)(B * C)) - mu * mu + BN_EPS);
  float v = xv[idx] + (pre[idx] - mu) * rs;
  xv[idx] = fmaxf(v, 0.f);
}

// ---------------- cosine classifier ----------------
__global__ __launch_bounds__(256)
void cl_k(const float* __restrict__ xv, const float* __restrict__ sc,
          float* __restrict__ out)
{
  const int bid = blockIdx.x;
  const int b = bid / N, i = bid % N;
  const int tid = threadIdx.x;
  float sxx = 0.f, sss = 0.f, sxs = 0.f;
  for (int c = tid; c < C; c += 256) {
    float xvv = xv[(long long)(b * N + i) * C + c];
    float scv = fmaxf(sc[i * C + c], 0.f);
    sxx += xvv * xvv; sss += scv * scv; sxs += xvv * scv;
  }
  for (int off = 32; off; off >>= 1) {
    sxx += __shfl_down(sxx, off);
    sss += __shfl_down(sss, off);
    sxs += __shfl_down(sxs, off);
  }
  __shared__ float r0[4], r1[4], r2[4];
  int wid = tid >> 6, lane = tid & 63;
  if (lane == 0) { r0[wid] = sxx; r1[wid] = sss; r2[wid] = sxs; }
  __syncthreads();
  if (tid == 0) {
    float a = r0[0] + r0[1] + r0[2] + r0[3];
    float s = r1[0] + r1[1] + r1[2] + r1[3];
    float p = r2[0] + r2[1] + r2[2] + r2[3];
    float nx = fmaxf(sqrtf(a), 1e-12f);
    float ns = fmaxf(sqrtf(s), 1e-12f);
    out[b * N + i] = p / (nx * ns);
  }
}

// ---------------- cl_edge = ed @ efc_w + efc_b ----------------
__global__ __launch_bounds__(64)
void cledge_k(const float* __restrict__ ed, const float* __restrict__ w,
              const float* __restrict__ bias, float* __restrict__ out)
{
  const int bid = blockIdx.x;
  const int lane = threadIdx.x;
  float a0 = 0, a1 = 0, a2 = 0, a3 = 0;
  for (int c = lane; c < C; c += 64) {
    float v = ed[(long long)bid * C + c];
    a0 = fmaf(v, w[c * 4 + 0], a0);
    a1 = fmaf(v, w[c * 4 + 1], a1);
    a2 = fmaf(v, w[c * 4 + 2], a2);
    a3 = fmaf(v, w[c * 4 + 3], a3);
  }
  for (int off = 32; off; off >>= 1) {
    a0 += __shfl_down(a0, off);
    a1 += __shfl_down(a1, off);
    a2 += __shfl_down(a2, off);
    a3 += __shfl_down(a3, off);
  }
  if (lane == 0) {
    out[B * N + bid * 4 + 0] = a0 + bias[0];
    out[B * N + bid * 4 + 1] = a1 + bias[1];
    out[B * N + bid * 4 + 2] = a2 + bias[2];
    out[B * N + bid * 4 + 3] = a3 + bias[3];
  }
}

} // namespace

extern "C" void kernel_launch(void* const* d_in, const int* in_sizes, int n_in,
                              void* d_out, int out_size, void* d_ws, size_t ws_size,
                              hipStream_t stream)
{
  (void)in_sizes; (void)n_in; (void)out_size; (void)ws_size;
  const float* x      = (const float*)d_in[0];
  const float* Wc     = (const float*)d_in[1];
  const float* bc     = (const float*)d_in[2];
  const float* fam_wq = (const float*)d_in[3];
  const float* fam_bq = (const float*)d_in[4];
  const float* fam_wk = (const float*)d_in[5];
  const float* fam_bk = (const float*)d_in[6];
  const float* fam_wv = (const float*)d_in[7];
  const float* fam_bv = (const float*)d_in[8];
  const float* arm_wq = (const float*)d_in[9];
  const float* arm_bq = (const float*)d_in[10];
  const float* arm_wk = (const float*)d_in[11];
  const float* arm_bk = (const float*)d_in[12];
  const float* arm_wv = (const float*)d_in[13];
  const float* arm_bv = (const float*)d_in[14];
  const float* ep_w   = (const float*)d_in[15];
  const float* ep_b   = (const float*)d_in[16];
  const float* gw[10] = {
    (const float*)d_in[17], (const float*)d_in[18], (const float*)d_in[19],
    (const float*)d_in[20], (const float*)d_in[21],
    (const float*)d_in[22], (const float*)d_in[23], (const float*)d_in[24],
    (const float*)d_in[25], (const float*)d_in[26]};
  const float* sc     = (const float*)d_in[27];
  const float* efc_w  = (const float*)d_in[28];
  const float* efc_b  = (const float*)d_in[29];
  float* out = (float*)d_out;

  char* wsb = (char*)d_ws;
  size_t off = 0;
  auto allocf = [&](size_t n) { float* p = (float*)(wsb + off); off += ((n * 4 + 255) / 256) * 256; return p; };
  auto allocu = [&](size_t n) { unsigned short* p = (unsigned short*)(wsb + off); off += ((n * 2 + 255) / 256) * 256; return p; };

  // region_a: h_t (2.41M f) early; Sc (2.77M f) later (h_t dead after fu_fv)
  float* region_a = allocf(2766336);
  float* h_t = region_a;
  float* Sc  = region_a;

  float* mu_h  = allocf(6144);
  float* rs_h  = allocf(6144);
  float* bnp_s = allocf(49152);
  float* bnp_q = allocf(49152);
  float* f_v   = allocf(49152);
  float* Sf    = allocf(230496);           // 8*588*49
  float* Gm    = allocf(230496);           // 96*49*49
  float* S1    = allocf(589824);
  float* fe    = allocf(589824);
  float* EW    = allocf(589824);
  float* W2    = allocf(262144);
  float* b2    = allocf(512);
  float* eS    = allocf(2304);
  float* me    = allocf(144);
  float* rve   = allocf(144);
  float* mask  = allocf(1152);
  float* ABUV  = allocf(196608);
  float* pre   = allocf(49152);
  float* mu_e  = allocf(144);
  float* rs_e  = allocf(144);
  float* nps   = allocf(96);
  float* npq   = allocf(96);
  float* kvbias = allocf(768);
  float* qkbias = allocf(512);

  unsigned short* Wct    = allocu(3145728);
  unsigned short* famqt  = allocu(131072);
  unsigned short* kvwt   = allocu(393216);   // [768][512]: fam_wk rows 0..255, fam_wv rows 256..767
  unsigned short* qkwt   = allocu(262144);   // [512][512]: arm_wq rows 0..255, arm_wk rows 256..511
  unsigned short* epwt   = allocu(262144);
  unsigned short* W2t    = allocu(262144);
  unsigned short* wet0   = allocu(262144);
  unsigned short* wet1   = allocu(262144);
  unsigned short* ABUVt0 = allocu(1048576);
  unsigned short* ABUVt1 = allocu(1048576);
  unsigned short* xb     = allocu(200704);
  unsigned short* fub    = allocu(2408448);
  unsigned short* q1b    = allocu(1204224);  // [4704][256]
  unsigned short* kxvx_b = allocu(350208);   // [456][768] (pad rows for B overread)
  unsigned short* Ppb    = allocu(301056);   // [4704][64]
  unsigned short* vxtb   = allocu(262144);   // [8][512][64]
  unsigned short* featb  = allocu(2408448);  // [4704][512]
  unsigned short* qkb    = allocu(2441216);  // [4768][512] (pad for Sc B overread)
  unsigned short* vfeb   = allocu(2441216);  // [4768][512] (pad for Gm B overread)

  dim3 blk(256);

  // -------- weight transpose+cast (28 jobs) --------
  TCJobs tj{};
  int jn = 0;
  for (int n = 0; n < 12; ++n) { tj.src[jn] = Wc + (size_t)n * C * C; tj.dst[jn] = Wct + (size_t)n * C * C; tj.nn[jn] = C; ++jn; }
  tj.src[jn] = fam_wq; tj.dst[jn] = famqt;            tj.nn[jn] = H; ++jn;
  tj.src[jn] = fam_wk; tj.dst[jn] = kvwt;             tj.nn[jn] = H; ++jn;
  tj.src[jn] = fam_wv; tj.dst[jn] = kvwt + 256 * 512; tj.nn[jn] = C; ++jn;
  tj.src[jn] = arm_wq; tj.dst[jn] = qkwt;             tj.nn[jn] = H; ++jn;
  tj.src[jn] = arm_wk; tj.dst[jn] = qkwt + 256 * 512; tj.nn[jn] = H; ++jn;
  tj.src[jn] = ep_w;   tj.dst[jn] = epwt;             tj.nn[jn] = C; ++jn;
  tj.src[jn] = gw[2];  tj.dst[jn] = wet0;             tj.nn[jn] = C; ++jn;
  tj.src[jn] = gw[7];  tj.dst[jn] = wet1;             tj.nn[jn] = C; ++jn;
  tj.src[jn] = gw[0];  tj.dst[jn] = ABUVt0;               tj.nn[jn] = C; ++jn;
  tj.src[jn] = gw[1];  tj.dst[jn] = ABUVt0 + 1 * C * C;   tj.nn[jn] = C; ++jn;
  tj.src[jn] = gw[3];  tj.dst[jn] = ABUVt0 + 2 * C * C;   tj.nn[jn] = C; ++jn;
  tj.src[jn] = gw[4];  tj.dst[jn] = ABUVt0 + 3 * C * C;   tj.nn[jn] = C; ++jn;
  tj.src[jn] = gw[5];  tj.dst[jn] = ABUVt1;               tj.nn[jn] = C; ++jn;
  tj.src[jn] = gw[6];  tj.dst[jn] = ABUVt1 + 1 * C * C;   tj.nn[jn] = C; ++jn;
  tj.src[jn] = gw[8];  tj.dst[jn] = ABUVt1 + 2 * C * C;   tj.nn[jn] = C; ++jn;
  tj.src[jn] = gw[9];  tj.dst[jn] = ABUVt1 + 3 * C * C;   tj.nn[jn] = C; ++jn;
  tcast_k<<<dim3(16, 16, 28), blk, 0, stream>>>(tj);

  castrow_k<<<dim3(98), blk, 0, stream>>>(x, xb, fam_bk, fam_bv, arm_bq, arm_bk, kvbias, qkbias);
  b2full_k<<<dim3(2), blk, 0, stream>>>(arm_bv, ep_w, ep_b, b2);

  // h[n] = x @ Wc[n] + bc[n]
  gemm_mfma<<<dim3(7, 8, 12), blk, 0, stream>>>(xb, Wct, bc, h_t, nullptr,
      M_BD, C, C, C, C, C, 1, 0LL, (long long)C * C, (long long)C, (long long)M_BD * C);
  bn_stats_part<<<dim3(24, 8), blk, 0, stream>>>(h_t, bnp_s, bnp_q);
  bn_stats_final<<<dim3(24), blk, 0, stream>>>(bnp_s, bnp_q, mu_h, rs_h);
  fu_fv<<<dim3(B * N, 2), blk, 0, stream>>>(h_t, mu_h, rs_h, fub, f_v);

  // fam projections (q1; merged kx|vx)
  gemm_mfma<<<dim3(74, 4, 1), blk, 0, stream>>>(fub, famqt, fam_bq, nullptr, q1b,
      M_BND, H, C, C, C, H, 1, 0, 0, 0, 0);
  gemm_mfma<<<dim3(7, 12, 1), blk, 0, stream>>>(xb, kvwt, kvbias, nullptr, kxvx_b,
      M_BD, 768, C, C, C, 768, 1, 0, 0, 0, 0);
  // Sf[b] = q1[b] @ kx[b]^T  (588 x 49)
  gemm_mfma<<<dim3(10, 1, 8), blk, 0, stream>>>(q1b, kxvx_b, nullptr, Sf, nullptr,
      588, 49, H, H, 768, 49, 1, 588LL * 256, 49LL * 768, 0LL, 588LL * 49);
  fam_softmax<<<dim3(19), blk, 0, stream>>>(Sf, Ppb);
  vxt_k<<<dim3(8, 8), blk, 0, stream>>>(kxvx_b, vxtb);
  // feat[b] = P[b] @ vx[b]  (588 x 512, K=64)
  gemm_mfma<<<dim3(10, 8, 8), blk, 0, stream>>>(Ppb, vxtb, nullptr, nullptr, featb,
      588, C, 64, 64, 64, C, 1, 588LL * 64, 512LL * 64, 0LL, 588LL * 512);

  // arm q|k merged projection
  gemm_mfma<<<dim3(74, 8, 1), blk, 0, stream>>>(featb, qkwt, qkbias, nullptr, qkb,
      M_BND, C, C, C, C, C, 1, 0, 0, 0, 0);
  // W2 = arm_wv @ ep_w ; vfe = feat @ W2 + b2 (ep_w folded through v)
  gemm_mfma<<<dim3(8, 8, 1), blk, 0, stream>>>(arm_wv, epwt, nullptr, W2, nullptr,
      C, C, C, C, C, C, 0, 0, 0, 0, 0);
  {
    TCJobs tj2{};
    tj2.src[0] = W2; tj2.dst[0] = W2t; tj2.nn[0] = C;
    tcast_k<<<dim3(16, 16, 1), blk, 0, stream>>>(tj2);
  }
  gemm_mfma<<<dim3(74, 8, 1), blk, 0, stream>>>(featb, W2t, b2, nullptr, vfeb,
      M_BND, C, C, C, C, C, 1, 0, 0, 0, 0);

  // Sc[b] = qf[b] @ kf[b]^T  (588 x 588); qf = qkb cols 0..255, kf = cols 256..511
  gemm_mfma<<<dim3(10, 10, 8), blk, 0, stream>>>(qkb, qkb + 256, nullptr, Sc, nullptr,
      588, 588, H, C, C, 588, 1, 588LL * 512, 588LL * 512, 0LL, 588LL * 588);
  // G[node] = vfe_node @ vfe_node^T  (49 x 49)
  gemm_mfma<<<dim3(1, 1, 96), blk, 0, stream>>>(vfeb, vfeb, nullptr, Gm, nullptr,
      D, D, C, C, C, D, 1, 49LL * 512, 49LL * 512, 0LL, 49LL * 49);

  // per-edge: softmax + colsum@V (S1) + st2 via MFMA
  edge_finish<<<dim3(B * E), blk, 0, stream>>>(Sc, Gm, vfeb, S1, eS);
  edge_me<<<dim3(1), blk, 0, stream>>>(eS, me, rve);
  mask_k<<<dim3(B), blk, 0, stream>>>(f_v, mask);
  fe_k<<<dim3((B * E * C + 255) / 256), blk, 0, stream>>>(S1, me, rve, mask, fe);

  // two GNN layers
  for (int L = 0; L < 2; ++L) {
    const unsigned short* ABUVt = L ? ABUVt1 : ABUVt0;
    const unsigned short* wet   = L ? wet1 : wet0;
    gemm_mfma<<<dim3(2, 32, 1), blk, 0, stream>>>(f_v, ABUVt, nullptr, ABUV, nullptr,
        B * N, 2048, C, C, C, 2048, 0, 0, 0, 0, 0);
    gemm_mfma<<<dim3(18, 8, 1), blk, 0, stream>>>(fe, wet, nullptr, EW, nullptr,
        B * E, C, C, C, C, C, 0, 0, 0, 0, 0);
    agg_stats<<<dim3(E), blk, 0, stream>>>(ABUV, EW, mu_e, rs_e);
    edmsg_k<<<dim3(B * N), blk, 0, stream>>>(fe, ABUV, EW, mu_e, rs_e, pre);
    node_part<<<dim3(N, B), blk, 0, stream>>>(pre, nps, npq);
    xv_update<<<dim3((B * N * C + 255) / 256), blk, 0, stream>>>(f_v, pre, nps, npq);
  }

  cl_k<<<dim3(B * N), blk, 0, stream>>>(f_v, sc, out);
  cledge_k<<<dim3(B * E), dim3(64), 0, stream>>>(fe, efc_w, efc_b, out);
}